// Round 11
// baseline (254.358 us; speedup 1.0000x reference)
//
#include <hip/hip_runtime.h>
#include <hip/hip_bf16.h>
#include <math.h>

typedef __bf16 bf16_t;
typedef __bf16 bf16x8 __attribute__((ext_vector_type(8)));
typedef __bf16 bf16x4 __attribute__((ext_vector_type(4)));
typedef float f32x4 __attribute__((ext_vector_type(4)));
typedef unsigned int u32;
typedef u32 u32x2 __attribute__((ext_vector_type(2)));

#define DM 1024
#define SEQL 2048
#define NTOK 4096
#define QKVN 3072

__device__ __forceinline__ void gload_lds16(const bf16_t* g, bf16_t* l){
  __builtin_amdgcn_global_load_lds((const __attribute__((address_space(1))) void*)g,
                                   (__attribute__((address_space(3))) void*)l, 16, 0, 0);
}
__device__ __forceinline__ u32 ldsoff(const void* p){
  return (u32)(size_t)(__attribute__((address_space(3))) const void*)p;
}
__device__ __forceinline__ u32x2 tr64(u32 byte_off){
  u32x2 d;
  asm volatile("ds_read_b64_tr_b16 %0, %1" : "=v"(d) : "v"(byte_off));
  return d;
}
__device__ __forceinline__ u32 pack2(float a, float b){
  union{ __bf16 h[2]; u32 w; } z;
  z.h[0]=(__bf16)a; z.h[1]=(__bf16)b; return z.w;
}

// ---------------- prep: all weight cvts (12M elems) + LN1, one launch ----------------
__global__ __launch_bounds__(256) void prep_kernel(
    const float* __restrict__ wq, const float* __restrict__ wk,
    const float* __restrict__ wv, const float* __restrict__ wo,
    const float* __restrict__ w1, const float* __restrict__ w2,
    const float* __restrict__ x,  const float* __restrict__ g1,
    const float* __restrict__ b1,
    bf16_t* __restrict__ wqkv_b, bf16_t* __restrict__ wo_b,
    bf16_t* __restrict__ w1_b,   bf16_t* __restrict__ w2_b,
    bf16_t* __restrict__ h1)
{
  __shared__ float red[8];
  const int bid = blockIdx.x;
  const int t = threadIdx.x;
  if (bid < 12288){
    const int flat = (bid*256 + t)*4;
    const int seg = flat >> 20;
    const int off1m = flat & 1048575;
    const float* src; bf16_t* dst;
    if (seg < 3){
      src = (seg==0 ? wq : (seg==1 ? wk : wv)) + off1m;
      dst = wqkv_b + flat;
    } else if (seg == 3){
      src = wo + off1m;  dst = wo_b + off1m;
    } else if (seg < 8){
      src = w1 + (flat - 4*1048576);  dst = w1_b + (flat - 4*1048576);
    } else {
      src = w2 + (flat - 8*1048576);  dst = w2_b + (flat - 8*1048576);
    }
    const float4 v = *(const float4*)src;
    bf16x4 o; o[0]=(__bf16)v.x; o[1]=(__bf16)v.y; o[2]=(__bf16)v.z; o[3]=(__bf16)v.w;
    *(bf16x4*)dst = o;
  } else {
    const int row = bid - 12288;
    const float4 v = *(const float4*)(x + (size_t)row*DM + t*4);
    float s  = v.x+v.y+v.z+v.w;
    float sq = v.x*v.x+v.y*v.y+v.z*v.z+v.w*v.w;
    #pragma unroll
    for (int m=1;m<64;m<<=1){ s += __shfl_xor(s,m); sq += __shfl_xor(sq,m); }
    const int w = t>>6;
    if ((t&63)==0){ red[w]=s; red[4+w]=sq; }
    __syncthreads();
    s  = red[0]+red[1]+red[2]+red[3];
    sq = red[4]+red[5]+red[6]+red[7];
    const float mean = s*(1.f/DM);
    const float var  = sq*(1.f/DM) - mean*mean;
    const float rstd = rsqrtf(var + 1e-5f);
    const float4 gg = *(const float4*)(g1 + t*4);
    const float4 bb = *(const float4*)(b1 + t*4);
    bf16x4 o;
    o[0]=(__bf16)((v.x-mean)*rstd*gg.x+bb.x);
    o[1]=(__bf16)((v.y-mean)*rstd*gg.y+bb.y);
    o[2]=(__bf16)((v.z-mean)*rstd*gg.z+bb.z);
    o[3]=(__bf16)((v.w-mean)*rstd*gg.w+bb.w);
    *(bf16x4*)(h1 + (size_t)row*DM + t*4) = o;
  }
}

// ---------------- LayerNorm (LN2, bf16 input) ----------------
__global__ __launch_bounds__(256) void lnb_kernel(const bf16_t* __restrict__ in,
    const float* __restrict__ g, const float* __restrict__ bta,
    bf16_t* __restrict__ outp)
{
  const int row = blockIdx.x;
  const int t = threadIdx.x;
  const bf16x4 raw = *(const bf16x4*)(in + (size_t)row*DM + t*4);
  float4 v;
  v.x=(float)raw[0]; v.y=(float)raw[1]; v.z=(float)raw[2]; v.w=(float)raw[3];
  float s  = v.x+v.y+v.z+v.w;
  float sq = v.x*v.x+v.y*v.y+v.z*v.z+v.w*v.w;
  #pragma unroll
  for (int m=1;m<64;m<<=1){ s += __shfl_xor(s,m); sq += __shfl_xor(sq,m); }
  __shared__ float red[8];
  const int w = t>>6;
  if ((t&63)==0){ red[w]=s; red[4+w]=sq; }
  __syncthreads();
  s  = red[0]+red[1]+red[2]+red[3];
  sq = red[4]+red[5]+red[6]+red[7];
  const float mean = s*(1.f/DM);
  const float var  = sq*(1.f/DM) - mean*mean;
  const float rstd = rsqrtf(var + 1e-5f);
  const float4 gg = *(const float4*)(g + t*4);
  const float4 bb = *(const float4*)(bta + t*4);
  bf16x4 o;
  o[0]=(__bf16)((v.x-mean)*rstd*gg.x+bb.x);
  o[1]=(__bf16)((v.y-mean)*rstd*gg.y+bb.y);
  o[2]=(__bf16)((v.z-mean)*rstd*gg.z+bb.z);
  o[3]=(__bf16)((v.w-mean)*rstd*gg.w+bb.w);
  *(bf16x4*)(outp + (size_t)row*DM + t*4) = o;
}

// ---------------- final reduce: out = x + sum of 4 bf16 partials ----------------
__global__ __launch_bounds__(256) void red4_kernel(
    const bf16_t* __restrict__ p0, const bf16_t* __restrict__ p1,
    const bf16_t* __restrict__ p2, const bf16_t* __restrict__ p3,
    const float* __restrict__ x, float* __restrict__ outp)
{
  const int i = (blockIdx.x*256 + threadIdx.x)*4;
  const bf16x4 a0 = *(const bf16x4*)(p0 + i);
  const bf16x4 a1 = *(const bf16x4*)(p1 + i);
  const bf16x4 a2 = *(const bf16x4*)(p2 + i);
  const bf16x4 a3 = *(const bf16x4*)(p3 + i);
  const float4 xs = *(const float4*)(x + i);
  float4 o;
  o.x = xs.x + ((float)a0[0]+(float)a1[0]) + ((float)a2[0]+(float)a3[0]);
  o.y = xs.y + ((float)a0[1]+(float)a1[1]) + ((float)a2[1]+(float)a3[1]);
  o.z = xs.z + ((float)a0[2]+(float)a1[2]) + ((float)a2[2]+(float)a3[2]);
  o.w = xs.w + ((float)a0[3]+(float)a1[3]) + ((float)a2[3]+(float)a3[3]);
  *(float4*)(outp + i) = o;
}

// ---------------- 256x256 8-phase GEMM (m201 template port, split-K capable) -----------
// A row stride = lda; per-block K window = [blockIdx.z*K, +K). Output per z: c0..c3.
template<int EPI>
__global__ __launch_bounds__(512, 2) void gemm8ph(
    const bf16_t* __restrict__ A, const bf16_t* __restrict__ Bw,
    void* __restrict__ c0, void* __restrict__ c1,
    void* __restrict__ c2, void* __restrict__ c3,
    int N, int K, int lda)
{
  __shared__ __align__(16) char ldsb[131072];
  const int tid = threadIdx.x, lane = tid&63, wid = tid>>6;
  const int q16 = lane&15, g = lane>>4;
  const int wm = wid>>2, wn = wid&3;

  const int flat = blockIdx.y*gridDim.x + blockIdx.x;
  const int xcd = flat&7, jj = flat>>3;
  const int NY = gridDim.y;
  const int jdiv = jj/NY, jmod = jj - jdiv*NY;
  const int bm = (xcd*2 + jdiv)*256, bn = jmod*256;
  const int sk = blockIdx.z;
  const int koff = sk*K;
  void* Cout = (sk==0) ? c0 : (sk==1) ? c1 : (sk==2) ? c2 : c3;

  int mloc, kloc;
  {
    const u32 L = tid*16;
    const u32 logical = L ^ (((L>>9)&1)<<5);
    mloc = (int)(logical>>6);
    kloc = (int)((logical&63)>>1);
  }
  const bf16_t* asrc = A  + (size_t)(bm + mloc)*lda + koff + kloc;
  const bf16_t* bsrc = Bw + (size_t)(bn + mloc)*lda + koff + kloc;
  const u32 laneOff = ((u32)(q16*64 + g*16)) ^ ((u32)(q16&8)<<2);

  f32x4 acc[8][4] = {};
  bf16x8 bv[4];

  auto stage = [&](int buf, int kh, int isB, int s){
    const bf16_t* src = isB ? bsrc : asrc;
    #pragma unroll
    for (int h2=0; h2<2; h2++)
      gload_lds16(src + (size_t)(h2*128)*lda + s*64 + kh*32,
                  (bf16_t*)(ldsb + buf*65536 + isB*32768 + kh*16384 + h2*8192 + tid*16));
  };

  stage(0,0,0,0); stage(0,0,1,0); stage(0,1,0,0); stage(0,1,1,0);
  stage(1,0,0,1); stage(1,0,1,1);
  asm volatile("s_waitcnt vmcnt(4)" ::: "memory");
  __builtin_amdgcn_s_barrier();

  const int NSTEP = K>>6;
  const int NIT = NSTEP>>1;

#define PHASE(BUF,KH,MH,DOST,SBUF,SKH,SISB,SSTEP,CK) { \
    bf16x8 av[4]; \
    const char* Ab_ = ldsb + (BUF)*65536 + (KH)*16384 + wm*8192; \
    _Pragma("unroll") for (int jx=0;jx<4;jx++) \
      av[jx] = *(const bf16x8*)(Ab_ + (((MH)*4+jx)<<10) + laneOff); \
    if ((MH)==0){ \
      const char* Bb_ = ldsb + (BUF)*65536 + 32768 + (KH)*16384 + (wn>>1)*8192; \
      _Pragma("unroll") for (int jx=0;jx<4;jx++) \
        bv[jx] = *(const bf16x8*)(Bb_ + ((((wn&1)*4)+jx)<<10) + laneOff); \
    } \
    if (DOST) stage(SBUF,SKH,SISB,SSTEP); \
    asm volatile("s_barrier" ::: "memory"); \
    asm volatile("s_waitcnt lgkmcnt(0)" ::: "memory"); \
    __builtin_amdgcn_s_setprio(1); \
    _Pragma("unroll") for (int jx=0;jx<4;jx++) \
      _Pragma("unroll") for (int j2=0;j2<4;j2++) \
        acc[(MH)*4+jx][j2] = __builtin_amdgcn_mfma_f32_16x16x32_bf16(av[jx], bv[j2], acc[(MH)*4+jx][j2],0,0,0); \
    __builtin_amdgcn_s_setprio(0); \
    if (CK){ if (nl) { asm volatile("s_waitcnt vmcnt(4)" ::: "memory"); } \
             else    { asm volatile("s_waitcnt vmcnt(0)" ::: "memory"); } } \
    asm volatile("s_barrier" ::: "memory"); }

  for (int it=0; it<NIT; it++){
    const int s0 = 2*it, s1 = s0+1;
    const bool nl = (it+1 < NIT);
    PHASE(0,0,0, 1,  1,1,0, s1,   0)
    PHASE(0,0,1, 1,  1,1,1, s1,   0)
    PHASE(0,1,0, nl, 0,0,0, s0+2, 0)
    PHASE(0,1,1, nl, 0,0,1, s0+2, 1)
    PHASE(1,0,0, nl, 0,1,0, s0+2, 0)
    PHASE(1,0,1, nl, 0,1,1, s0+2, 0)
    PHASE(1,1,0, nl, 1,0,0, s1+2, 0)
    PHASE(1,1,1, nl, 1,0,1, s1+2, 1)
  }
#undef PHASE

  #pragma unroll
  for (int fm=0; fm<8; fm++)
    #pragma unroll
    for (int fn=0; fn<4; fn++)
      #pragma unroll
      for (int i=0; i<4; i++){
        const int r = bm + wm*128 + fm*16 + g*4 + i;
        const int c = bn + wn*64 + fn*16 + q16;
        const size_t idx = (size_t)r*N + c;
        const float vv = acc[fm][fn][i];
        if constexpr (EPI==0){
          ((bf16_t*)Cout)[idx] = (__bf16)vv;
        } else {
          const float ge = 0.5f*vv*(1.0f + erff(vv*0.70710678118654752f));
          ((bf16_t*)Cout)[idx] = (__bf16)ge;
        }
      }
}

// ---------------- 128x128 phase-split GEMM (WO) --------------------
// EPI=0: store bf16(X + C)
template<int EPI>
__global__ __launch_bounds__(512, 2) void gemm128(
    const bf16_t* __restrict__ A, const bf16_t* __restrict__ Bw,
    void* __restrict__ Cout, const float* __restrict__ X,
    int N, int K)
{
  constexpr int BK = 32;
  __shared__ __align__(16) char ldsb[3*16384];   // 48 KB
  const int tid = threadIdx.x, lane = tid&63, wid = tid>>6;
  const int q16 = lane&15, g = lane>>4;
  const int wm = wid>>2, wn = wid&3;

  const int flat = blockIdx.y*gridDim.x + blockIdx.x;   // grid 32x8 = 256
  const int xcd = flat&7, j = flat>>3;
  const int bm = ((xcd<<2) + (j>>3))*128, bn = (j&7)*128;

  int mloc, kloc;
  {
    const u32 L = tid*16;
    const u32 logical = L ^ (((L>>9)&1)<<5);
    mloc = (int)(logical>>6);
    kloc = (int)((logical&63)>>1);
  }
  const bf16_t* asrc = A  + (size_t)(bm + mloc)*K + kloc;
  const bf16_t* bsrc = Bw + (size_t)(bn + mloc)*K + kloc;
  const u32 laneOff = ((u32)(q16*64 + g*16)) ^ ((u32)(q16&8)<<2);

  f32x4 acc[4][2] = {};

  auto stageA = [&](int buf, int k0){
    gload_lds16(asrc + k0, (bf16_t*)(ldsb + buf*16384 + tid*16));
  };
  auto stageB = [&](int buf, int k0){
    gload_lds16(bsrc + k0, (bf16_t*)(ldsb + buf*16384 + 8192 + tid*16));
  };

  stageA(0,0); stageB(0,0);
  stageA(1,BK); stageB(1,BK);
  asm volatile("s_waitcnt vmcnt(2)" ::: "memory");
  __builtin_amdgcn_s_barrier();

  const int NT = K/BK;
  int bcur = 0;
  for (int kt=0; kt<NT; kt++){
    const int bstg = (bcur >= 1) ? bcur-1 : bcur+2;
    const char* Ab = ldsb + bcur*16384 + wm*4096;
    const char* Bb = ldsb + bcur*16384 + 8192 + wn*2048;
    const bool sOK = (kt+2 < NT);
    const int k0s = (kt+2)*BK;
    bf16x8 bv[2];
    #pragma unroll
    for (int p=0; p<2; p++){
      bf16x8 av[2];
      #pragma unroll
      for (int jx=0;jx<2;jx++)
        av[jx] = *(const bf16x8*)(Ab + ((p*2+jx)<<10) + laneOff);
      if (p==0){
        #pragma unroll
        for (int jx=0;jx<2;jx++)
          bv[jx] = *(const bf16x8*)(Bb + (jx<<10) + laneOff);
      }
      if (sOK){
        if (p==0) stageA(bstg,k0s);
        else      stageB(bstg,k0s);
      }
      asm volatile("s_barrier" ::: "memory");
      __builtin_amdgcn_s_setprio(1);
      #pragma unroll
      for (int jx=0;jx<2;jx++)
        #pragma unroll
        for (int j2=0;j2<2;j2++)
          acc[p*2+jx][j2] = __builtin_amdgcn_mfma_f32_16x16x32_bf16(av[jx], bv[j2], acc[p*2+jx][j2], 0,0,0);
      __builtin_amdgcn_s_setprio(0);
      if (p==1){
        if (sOK) asm volatile("s_waitcnt vmcnt(2)" ::: "memory");
        else     asm volatile("s_waitcnt vmcnt(0)" ::: "memory");
      }
      asm volatile("s_barrier" ::: "memory");
    }
    bcur = (bcur==2)?0:bcur+1;
  }

  #pragma unroll
  for (int fm=0; fm<4; fm++)
    #pragma unroll
    for (int fn=0; fn<2; fn++)
      #pragma unroll
      for (int i=0; i<4; i++){
        const int r = bm + wm*64 + fm*16 + g*4 + i;
        const int c = bn + wn*32 + fn*16 + q16;
        const size_t idx = (size_t)r*N + c;
        const float vv = X[idx] + acc[fm][fn][i];
        ((bf16_t*)Cout)[idx] = (__bf16)vv;
      }
}

// ---------------- Flash attention v7: 256 thr (4 waves), 4 blocks/CU ----------------
// 4 waves x 16 q-rows = 64 q-rows/block; grid (32, 32) = 1024 blocks.
// Swapped QK^T; in-register softmax (raw v_exp_f32, exp2 domain); P via shfl;
// K via global_load_lds (pre-swizzled source); V reg-staged (2 row-halves).
__global__ __launch_bounds__(256, 4) void attn_kernel(
    const bf16_t* __restrict__ QKV, bf16_t* __restrict__ Ctx)
{
  __shared__ __align__(16) bf16_t Ks[2][64*64];
  __shared__ __align__(16) bf16_t Vs[2][16*4*72];
  const int tid = threadIdx.x, lane = tid&63, w = tid>>6;
  const int g = lane>>4, q16 = lane&15;
  const int bh = blockIdx.y, b = bh>>4, h = bh&15;
  const int qr0 = blockIdx.x*64 + w*16;
  const size_t tok0 = (size_t)b*SEQL;
  const int ch0 = h*64;

  bf16x8 aq[2];
  #pragma unroll
  for (int ks=0; ks<2; ks++){
    bf16x8 t = *(const bf16x8*)(QKV + (tok0+qr0+q16)*QKVN + ch0 + ks*32 + g*8);
    #pragma unroll
    for (int jx=0;jx<8;jx++) t[jx] = (__bf16)((float)t[jx]*0.18033688f);
    aq[ks] = t;
  }

  const int srow = tid>>3, sc8 = (tid&7)*8;   // rows 0..31; +32 on second pass
  const bf16_t* kptr_swz = QKV + (tok0+srow)*QKVN + 1024 + ch0 + (sc8 ^ ((srow&7)<<3));
  const bf16_t* vptr = QKV + (tok0+srow)*QKVN + 2048 + ch0 + sc8;
  const int vwoff = ((srow>>2)*4 + (sc8>>4))*72 + (srow&3)*16 + (sc8&15);

  float mrun = -1e30f, lrun = 0.f;
  f32x4 o[4] = {};

  // prologue
  #pragma unroll
  for (int it=0; it<2; it++)
    gload_lds16(kptr_swz + (size_t)(it*32)*QKVN, &Ks[0][(tid + it*256)*8]);
  bf16x8 vreg[2];
  #pragma unroll
  for (int it=0; it<2; it++)
    vreg[it] = *(const bf16x8*)(vptr + (size_t)(it*32)*QKVN);
  #pragma unroll
  for (int it=0; it<2; it++)
    *(bf16x8*)&Vs[0][vwoff + it*2304] = vreg[it];
  #pragma unroll
  for (int it=0; it<2; it++)
    vreg[it] = *(const bf16x8*)(vptr + (size_t)(64 + it*32)*QKVN);

  const int NT = SEQL/64;
  for (int t=0; t<NT; t++){
    __syncthreads();
    if (t+1 < NT){
      #pragma unroll
      for (int it=0; it<2; it++){
        gload_lds16(kptr_swz + (size_t)((t+1)*64 + it*32)*QKVN, &Ks[(t+1)&1][(tid + it*256)*8]);
        *(bf16x8*)&Vs[(t+1)&1][vwoff + it*2304] = vreg[it];
      }
      if (t+2 < NT){
        #pragma unroll
        for (int it=0; it<2; it++)
          vreg[it] = *(const bf16x8*)(vptr + (size_t)((t+2)*64 + it*32)*QKVN);
      }
    }
    const bf16_t* ksb = Ks[t&1];
    const u32 vs0 = ldsoff(&Vs[t&1][0]);

    // ---- S^T = K (Q*0.125*log2e)^T ----
    f32x4 s[4] = {};
    #pragma unroll
    for (int ks=0; ks<2; ks++){
      #pragma unroll
      for (int fn=0; fn<4; fn++){
        const int r = fn*16 + q16;
        const int ce = ks*32 + g*8;
        bf16x8 bk = *(const bf16x8*)&ksb[r*64 + (ce ^ ((r&7)<<3))];
        s[fn] = __builtin_amdgcn_mfma_f32_16x16x32_bf16(bk, aq[ks], s[fn], 0, 0, 0);
      }
    }

    // ---- in-register online softmax ----
    float m0 = fmaxf(fmaxf(s[0][0],s[0][1]), fmaxf(s[0][2],s[0][3]));
    float m1 = fmaxf(fmaxf(s[1][0],s[1][1]), fmaxf(s[1][2],s[1][3]));
    float m2 = fmaxf(fmaxf(s[2][0],s[2][1]), fmaxf(s[2][2],s[2][3]));
    float m3 = fmaxf(fmaxf(s[3][0],s[3][1]), fmaxf(s[3][2],s[3][3]));
    float mx = fmaxf(fmaxf(m0,m1), fmaxf(m2,m3));
    mx = fmaxf(mx, __shfl_xor(mx,16));
    mx = fmaxf(mx, __shfl_xor(mx,32));

    if (!__all(mx <= mrun + 11.54f)){
      const float mnew = fmaxf(mrun, mx);
      const float alpha = __builtin_amdgcn_exp2f(mrun - mnew);
      #pragma unroll
      for (int i=0;i<4;i++){
        const float ai = __shfl(alpha, g*4+i);
        o[0][i]*=ai; o[1][i]*=ai; o[2][i]*=ai; o[3][i]*=ai;
      }
      lrun *= alpha;
      mrun = mnew;
    }

    float rs = 0.f;
    u32 u[4][2];
    #pragma unroll
    for (int fn=0; fn<4; fn++){
      const float e0=__builtin_amdgcn_exp2f(s[fn][0]-mrun);
      const float e1=__builtin_amdgcn_exp2f(s[fn][1]-mrun);
      const float e2=__builtin_amdgcn_exp2f(s[fn][2]-mrun);
      const float e3=__builtin_amdgcn_exp2f(s[fn][3]-mrun);
      rs += (e0+e1)+(e2+e3);
      u[fn][0] = pack2(e0,e1);
      u[fn][1] = pack2(e2,e3);
    }
    rs += __shfl_xor(rs,16);
    rs += __shfl_xor(rs,32);
    lrun += rs;

    // ---- O += P V ----
    #pragma unroll
    for (int ks=0; ks<2; ks++){
      u32x2 vlo[4], vhi[4];
      #pragma unroll
      for (int ne=0; ne<4; ne++){
        const u32 vb = vs0 + (u32)((((ks*8 + 2*g)*4 + ne)*72 + q16)*2);
        vlo[ne] = tr64(vb);
        vhi[ne] = tr64(vb + 576);
      }
      union { u32 wd[4]; bf16x8 v; } pa;
      #pragma unroll
      for (int jj=0; jj<4; jj++){
        const int src = q16 + ((((g&1)<<1) + (jj>>1))<<4);
        const u32 a0 = (u32)__shfl((int)u[2*ks  ][jj&1], src);
        const u32 a1 = (u32)__shfl((int)u[2*ks+1][jj&1], src);
        pa.wd[jj] = (g&2) ? a1 : a0;
      }
      asm volatile("s_waitcnt lgkmcnt(0)" ::: "memory");
      __builtin_amdgcn_sched_barrier(0);
      union { u32x2 u2[2]; bf16x8 v; } cc;
      #pragma unroll
      for (int ne=0; ne<4; ne++){
        cc.u2[0]=vlo[ne]; cc.u2[1]=vhi[ne];
        o[ne] = __builtin_amdgcn_mfma_f32_16x16x32_bf16(pa.v, cc.v, o[ne], 0, 0, 0);
      }
    }
  }

  const float rl = 1.0f/lrun;
  #pragma unroll
  for (int i=0; i<4; i++){
    const float ri = __shfl(rl, g*4+i);
    #pragma unroll
    for (int ne=0; ne<4; ne++){
      const int r = qr0 + g*4 + i;
      Ctx[(tok0+r)*DM + ch0 + ne*16 + q16] = (__bf16)(o[ne][i]*ri);
    }
  }
}

// ---------------- launcher ----------------
extern "C" void kernel_launch(void* const* d_in, const int* in_sizes, int n_in,
                              void* d_out, int out_size, void* d_ws, size_t ws_size,
                              hipStream_t stream)
{
  (void)in_sizes; (void)n_in; (void)out_size; (void)ws_size;
  const float* x  = (const float*)d_in[0];
  const float* wq = (const float*)d_in[1];
  const float* wk = (const float*)d_in[2];
  const float* wv = (const float*)d_in[3];
  const float* wo = (const float*)d_in[4];
  const float* w1 = (const float*)d_in[5];
  const float* w2 = (const float*)d_in[6];
  const float* g1 = (const float*)d_in[7];
  const float* b1 = (const float*)d_in[8];
  const float* g2 = (const float*)d_in[9];
  const float* b2 = (const float*)d_in[10];
  float* out = (float*)d_out;
  char* ws = (char*)d_ws;
  const size_t MB = 1024ull*1024ull;

  bf16_t* wqkv_b = (bf16_t*)(ws);            // 6 MB  [3072][1024]
  bf16_t* wo_b   = (bf16_t*)(ws + 6*MB);     // 2 MB
  bf16_t* w1_b   = (bf16_t*)(ws + 8*MB);     // 8 MB
  bf16_t* w2_b   = (bf16_t*)(ws + 16*MB);    // 8 MB
  bf16_t* h1     = (bf16_t*)(ws + 24*MB);    // 8 MB
  bf16_t* qkv    = (bf16_t*)(ws + 32*MB);    // 24 MB [4096][3072]
  bf16_t* ctx    = (bf16_t*)(ws + 56*MB);    // 8 MB
  bf16_t* res2b  = (bf16_t*)(ws + 64*MB);    // 8 MB (bf16 x+attn residual)
  bf16_t* h2     = h1;                       // alias: h1 dead after QKV GEMM
  bf16_t* ffm    = (bf16_t*)(ws + 32*MB);    // 32 MB, alias qkv+ctx (dead by then)
  // FF2 split-K partials (all regions dead by FF2 time):
  bf16_t* p0     = (bf16_t*)(ws);            // 8 MB (wqkv_b dead)
  bf16_t* p1     = (bf16_t*)(ws + 8*MB);     // 8 MB (w1_b dead after FF1)
  bf16_t* p2     = (bf16_t*)(ws + 24*MB);    // 8 MB (h1/h2 dead after FF1)
  bf16_t* p3     = (bf16_t*)(ws + 64*MB);    // 8 MB (res2b dead after LN2)

  prep_kernel<<<16384, 256, 0, stream>>>(wq, wk, wv, wo, w1, w2, x, g1, b1,
                                         wqkv_b, wo_b, w1_b, w2_b, h1);
  gemm8ph<0><<<dim3(16, 12), 512, 0, stream>>>(h1, wqkv_b, (void*)qkv, (void*)qkv,
                                               (void*)qkv, (void*)qkv, QKVN, 1024, 1024);
  attn_kernel<<<dim3(32, 32), 256, 0, stream>>>(qkv, ctx);
  gemm128<0><<<dim3(32, 8), 512, 0, stream>>>(ctx, wo_b, (void*)res2b, x, 1024, 1024);
  lnb_kernel<<<NTOK, 256, 0, stream>>>(res2b, g2, b2, h2);
  gemm8ph<2><<<dim3(16, 16), 512, 0, stream>>>(h2, w1_b, (void*)ffm, (void*)ffm,
                                               (void*)ffm, (void*)ffm, 4096, 1024, 1024);
  gemm8ph<0><<<dim3(16, 4, 4), 512, 0, stream>>>(ffm, w2_b, (void*)p0, (void*)p1,
                                                 (void*)p2, (void*)p3, 1024, 1024, 4096);
  red4_kernel<<<4096, 256, 0, stream>>>(p0, p1, p2, p3, x, out);
}

// Round 12
// 244.096 us; speedup vs baseline: 1.0420x; 1.0420x over previous
//
#include <hip/hip_runtime.h>
#include <hip/hip_bf16.h>
#include <math.h>

typedef __bf16 bf16_t;
typedef __bf16 bf16x8 __attribute__((ext_vector_type(8)));
typedef __bf16 bf16x4 __attribute__((ext_vector_type(4)));
typedef float f32x4 __attribute__((ext_vector_type(4)));
typedef unsigned int u32;
typedef u32 u32x2 __attribute__((ext_vector_type(2)));

#define DM 1024
#define SEQL 2048
#define NTOK 4096
#define QKVN 3072

__device__ __forceinline__ void gload_lds16(const bf16_t* g, bf16_t* l){
  __builtin_amdgcn_global_load_lds((const __attribute__((address_space(1))) void*)g,
                                   (__attribute__((address_space(3))) void*)l, 16, 0, 0);
}
__device__ __forceinline__ u32 ldsoff(const void* p){
  return (u32)(size_t)(__attribute__((address_space(3))) const void*)p;
}
__device__ __forceinline__ u32x2 tr64(u32 byte_off){
  u32x2 d;
  asm volatile("ds_read_b64_tr_b16 %0, %1" : "=v"(d) : "v"(byte_off));
  return d;
}
__device__ __forceinline__ u32 pack2(float a, float b){
  union{ __bf16 h[2]; u32 w; } z;
  z.h[0]=(__bf16)a; z.h[1]=(__bf16)b; return z.w;
}

// ---------------- prep: all weight cvts (12M elems) + LN1, one launch ----------------
__global__ __launch_bounds__(256) void prep_kernel(
    const float* __restrict__ wq, const float* __restrict__ wk,
    const float* __restrict__ wv, const float* __restrict__ wo,
    const float* __restrict__ w1, const float* __restrict__ w2,
    const float* __restrict__ x,  const float* __restrict__ g1,
    const float* __restrict__ b1,
    bf16_t* __restrict__ wqkv_b, bf16_t* __restrict__ wo_b,
    bf16_t* __restrict__ w1_b,   bf16_t* __restrict__ w2_b,
    bf16_t* __restrict__ h1)
{
  __shared__ float red[8];
  const int bid = blockIdx.x;
  const int t = threadIdx.x;
  if (bid < 12288){
    const int flat = (bid*256 + t)*4;
    const int seg = flat >> 20;
    const int off1m = flat & 1048575;
    const float* src; bf16_t* dst;
    if (seg < 3){
      src = (seg==0 ? wq : (seg==1 ? wk : wv)) + off1m;
      dst = wqkv_b + flat;
    } else if (seg == 3){
      src = wo + off1m;  dst = wo_b + off1m;
    } else if (seg < 8){
      src = w1 + (flat - 4*1048576);  dst = w1_b + (flat - 4*1048576);
    } else {
      src = w2 + (flat - 8*1048576);  dst = w2_b + (flat - 8*1048576);
    }
    const float4 v = *(const float4*)src;
    bf16x4 o; o[0]=(__bf16)v.x; o[1]=(__bf16)v.y; o[2]=(__bf16)v.z; o[3]=(__bf16)v.w;
    *(bf16x4*)dst = o;
  } else {
    const int row = bid - 12288;
    const float4 v = *(const float4*)(x + (size_t)row*DM + t*4);
    float s  = v.x+v.y+v.z+v.w;
    float sq = v.x*v.x+v.y*v.y+v.z*v.z+v.w*v.w;
    #pragma unroll
    for (int m=1;m<64;m<<=1){ s += __shfl_xor(s,m); sq += __shfl_xor(sq,m); }
    const int w = t>>6;
    if ((t&63)==0){ red[w]=s; red[4+w]=sq; }
    __syncthreads();
    s  = red[0]+red[1]+red[2]+red[3];
    sq = red[4]+red[5]+red[6]+red[7];
    const float mean = s*(1.f/DM);
    const float var  = sq*(1.f/DM) - mean*mean;
    const float rstd = rsqrtf(var + 1e-5f);
    const float4 gg = *(const float4*)(g1 + t*4);
    const float4 bb = *(const float4*)(b1 + t*4);
    bf16x4 o;
    o[0]=(__bf16)((v.x-mean)*rstd*gg.x+bb.x);
    o[1]=(__bf16)((v.y-mean)*rstd*gg.y+bb.y);
    o[2]=(__bf16)((v.z-mean)*rstd*gg.z+bb.z);
    o[3]=(__bf16)((v.w-mean)*rstd*gg.w+bb.w);
    *(bf16x4*)(h1 + (size_t)row*DM + t*4) = o;
  }
}

// ---------------- LayerNorm (LN2, bf16 input) ----------------
__global__ __launch_bounds__(256) void lnb_kernel(const bf16_t* __restrict__ in,
    const float* __restrict__ g, const float* __restrict__ bta,
    bf16_t* __restrict__ outp)
{
  const int row = blockIdx.x;
  const int t = threadIdx.x;
  const bf16x4 raw = *(const bf16x4*)(in + (size_t)row*DM + t*4);
  float4 v;
  v.x=(float)raw[0]; v.y=(float)raw[1]; v.z=(float)raw[2]; v.w=(float)raw[3];
  float s  = v.x+v.y+v.z+v.w;
  float sq = v.x*v.x+v.y*v.y+v.z*v.z+v.w*v.w;
  #pragma unroll
  for (int m=1;m<64;m<<=1){ s += __shfl_xor(s,m); sq += __shfl_xor(sq,m); }
  __shared__ float red[8];
  const int w = t>>6;
  if ((t&63)==0){ red[w]=s; red[4+w]=sq; }
  __syncthreads();
  s  = red[0]+red[1]+red[2]+red[3];
  sq = red[4]+red[5]+red[6]+red[7];
  const float mean = s*(1.f/DM);
  const float var  = sq*(1.f/DM) - mean*mean;
  const float rstd = rsqrtf(var + 1e-5f);
  const float4 gg = *(const float4*)(g + t*4);
  const float4 bb = *(const float4*)(bta + t*4);
  bf16x4 o;
  o[0]=(__bf16)((v.x-mean)*rstd*gg.x+bb.x);
  o[1]=(__bf16)((v.y-mean)*rstd*gg.y+bb.y);
  o[2]=(__bf16)((v.z-mean)*rstd*gg.z+bb.z);
  o[3]=(__bf16)((v.w-mean)*rstd*gg.w+bb.w);
  *(bf16x4*)(outp + (size_t)row*DM + t*4) = o;
}

// ---------------- final reduce: out = x + sum of 4 bf16 partials ----------------
__global__ __launch_bounds__(256) void red4_kernel(
    const bf16_t* __restrict__ p0, const bf16_t* __restrict__ p1,
    const bf16_t* __restrict__ p2, const bf16_t* __restrict__ p3,
    const float* __restrict__ x, float* __restrict__ outp)
{
  const int i = (blockIdx.x*256 + threadIdx.x)*4;
  const bf16x4 a0 = *(const bf16x4*)(p0 + i);
  const bf16x4 a1 = *(const bf16x4*)(p1 + i);
  const bf16x4 a2 = *(const bf16x4*)(p2 + i);
  const bf16x4 a3 = *(const bf16x4*)(p3 + i);
  const float4 xs = *(const float4*)(x + i);
  float4 o;
  o.x = xs.x + ((float)a0[0]+(float)a1[0]) + ((float)a2[0]+(float)a3[0]);
  o.y = xs.y + ((float)a0[1]+(float)a1[1]) + ((float)a2[1]+(float)a3[1]);
  o.z = xs.z + ((float)a0[2]+(float)a1[2]) + ((float)a2[2]+(float)a3[2]);
  o.w = xs.w + ((float)a0[3]+(float)a1[3]) + ((float)a2[3]+(float)a3[3]);
  *(float4*)(outp + i) = o;
}

// ---------------- 256x256 8-phase GEMM (m201 template port, split-K capable) -----------
template<int EPI>
__global__ __launch_bounds__(512, 2) void gemm8ph(
    const bf16_t* __restrict__ A, const bf16_t* __restrict__ Bw,
    void* __restrict__ c0, void* __restrict__ c1,
    void* __restrict__ c2, void* __restrict__ c3,
    int N, int K, int lda)
{
  __shared__ __align__(16) char ldsb[131072];
  const int tid = threadIdx.x, lane = tid&63, wid = tid>>6;
  const int q16 = lane&15, g = lane>>4;
  const int wm = wid>>2, wn = wid&3;

  const int flat = blockIdx.y*gridDim.x + blockIdx.x;
  const int xcd = flat&7, jj = flat>>3;
  const int NY = gridDim.y;
  const int jdiv = jj/NY, jmod = jj - jdiv*NY;
  const int bm = (xcd*2 + jdiv)*256, bn = jmod*256;
  const int sk = blockIdx.z;
  const int koff = sk*K;
  void* Cout = (sk==0) ? c0 : (sk==1) ? c1 : (sk==2) ? c2 : c3;

  int mloc, kloc;
  {
    const u32 L = tid*16;
    const u32 logical = L ^ (((L>>9)&1)<<5);
    mloc = (int)(logical>>6);
    kloc = (int)((logical&63)>>1);
  }
  const bf16_t* asrc = A  + (size_t)(bm + mloc)*lda + koff + kloc;
  const bf16_t* bsrc = Bw + (size_t)(bn + mloc)*lda + koff + kloc;
  const u32 laneOff = ((u32)(q16*64 + g*16)) ^ ((u32)(q16&8)<<2);

  f32x4 acc[8][4] = {};
  bf16x8 bv[4];

  auto stage = [&](int buf, int kh, int isB, int s){
    const bf16_t* src = isB ? bsrc : asrc;
    #pragma unroll
    for (int h2=0; h2<2; h2++)
      gload_lds16(src + (size_t)(h2*128)*lda + s*64 + kh*32,
                  (bf16_t*)(ldsb + buf*65536 + isB*32768 + kh*16384 + h2*8192 + tid*16));
  };

  stage(0,0,0,0); stage(0,0,1,0); stage(0,1,0,0); stage(0,1,1,0);
  stage(1,0,0,1); stage(1,0,1,1);
  asm volatile("s_waitcnt vmcnt(4)" ::: "memory");
  __builtin_amdgcn_s_barrier();

  const int NSTEP = K>>6;
  const int NIT = NSTEP>>1;

#define PHASE(BUF,KH,MH,DOST,SBUF,SKH,SISB,SSTEP,CK) { \
    bf16x8 av[4]; \
    const char* Ab_ = ldsb + (BUF)*65536 + (KH)*16384 + wm*8192; \
    _Pragma("unroll") for (int jx=0;jx<4;jx++) \
      av[jx] = *(const bf16x8*)(Ab_ + (((MH)*4+jx)<<10) + laneOff); \
    if ((MH)==0){ \
      const char* Bb_ = ldsb + (BUF)*65536 + 32768 + (KH)*16384 + (wn>>1)*8192; \
      _Pragma("unroll") for (int jx=0;jx<4;jx++) \
        bv[jx] = *(const bf16x8*)(Bb_ + ((((wn&1)*4)+jx)<<10) + laneOff); \
    } \
    if (DOST) stage(SBUF,SKH,SISB,SSTEP); \
    asm volatile("s_barrier" ::: "memory"); \
    asm volatile("s_waitcnt lgkmcnt(0)" ::: "memory"); \
    __builtin_amdgcn_s_setprio(1); \
    _Pragma("unroll") for (int jx=0;jx<4;jx++) \
      _Pragma("unroll") for (int j2=0;j2<4;j2++) \
        acc[(MH)*4+jx][j2] = __builtin_amdgcn_mfma_f32_16x16x32_bf16(av[jx], bv[j2], acc[(MH)*4+jx][j2],0,0,0); \
    __builtin_amdgcn_s_setprio(0); \
    if (CK){ if (nl) { asm volatile("s_waitcnt vmcnt(4)" ::: "memory"); } \
             else    { asm volatile("s_waitcnt vmcnt(0)" ::: "memory"); } } \
    asm volatile("s_barrier" ::: "memory"); }

  for (int it=0; it<NIT; it++){
    const int s0 = 2*it, s1 = s0+1;
    const bool nl = (it+1 < NIT);
    PHASE(0,0,0, 1,  1,1,0, s1,   0)
    PHASE(0,0,1, 1,  1,1,1, s1,   0)
    PHASE(0,1,0, nl, 0,0,0, s0+2, 0)
    PHASE(0,1,1, nl, 0,0,1, s0+2, 1)
    PHASE(1,0,0, nl, 0,1,0, s0+2, 0)
    PHASE(1,0,1, nl, 0,1,1, s0+2, 0)
    PHASE(1,1,0, nl, 1,0,0, s1+2, 0)
    PHASE(1,1,1, nl, 1,0,1, s1+2, 1)
  }
#undef PHASE

  #pragma unroll
  for (int fm=0; fm<8; fm++)
    #pragma unroll
    for (int fn=0; fn<4; fn++)
      #pragma unroll
      for (int i=0; i<4; i++){
        const int r = bm + wm*128 + fm*16 + g*4 + i;
        const int c = bn + wn*64 + fn*16 + q16;
        const size_t idx = (size_t)r*N + c;
        const float vv = acc[fm][fn][i];
        if constexpr (EPI==0){
          ((bf16_t*)Cout)[idx] = (__bf16)vv;
        } else {
          const float ge = 0.5f*vv*(1.0f + erff(vv*0.70710678118654752f));
          ((bf16_t*)Cout)[idx] = (__bf16)ge;
        }
      }
}

// ---------------- 128x128 phase-split GEMM (WO) --------------------
template<int EPI>
__global__ __launch_bounds__(512, 2) void gemm128(
    const bf16_t* __restrict__ A, const bf16_t* __restrict__ Bw,
    void* __restrict__ Cout, const float* __restrict__ X,
    int N, int K)
{
  constexpr int BK = 32;
  __shared__ __align__(16) char ldsb[3*16384];   // 48 KB
  const int tid = threadIdx.x, lane = tid&63, wid = tid>>6;
  const int q16 = lane&15, g = lane>>4;
  const int wm = wid>>2, wn = wid&3;

  const int flat = blockIdx.y*gridDim.x + blockIdx.x;   // grid 32x8 = 256
  const int xcd = flat&7, j = flat>>3;
  const int bm = ((xcd<<2) + (j>>3))*128, bn = (j&7)*128;

  int mloc, kloc;
  {
    const u32 L = tid*16;
    const u32 logical = L ^ (((L>>9)&1)<<5);
    mloc = (int)(logical>>6);
    kloc = (int)((logical&63)>>1);
  }
  const bf16_t* asrc = A  + (size_t)(bm + mloc)*K + kloc;
  const bf16_t* bsrc = Bw + (size_t)(bn + mloc)*K + kloc;
  const u32 laneOff = ((u32)(q16*64 + g*16)) ^ ((u32)(q16&8)<<2);

  f32x4 acc[4][2] = {};

  auto stageA = [&](int buf, int k0){
    gload_lds16(asrc + k0, (bf16_t*)(ldsb + buf*16384 + tid*16));
  };
  auto stageB = [&](int buf, int k0){
    gload_lds16(bsrc + k0, (bf16_t*)(ldsb + buf*16384 + 8192 + tid*16));
  };

  stageA(0,0); stageB(0,0);
  stageA(1,BK); stageB(1,BK);
  asm volatile("s_waitcnt vmcnt(2)" ::: "memory");
  __builtin_amdgcn_s_barrier();

  const int NT = K/BK;
  int bcur = 0;
  for (int kt=0; kt<NT; kt++){
    const int bstg = (bcur >= 1) ? bcur-1 : bcur+2;
    const char* Ab = ldsb + bcur*16384 + wm*4096;
    const char* Bb = ldsb + bcur*16384 + 8192 + wn*2048;
    const bool sOK = (kt+2 < NT);
    const int k0s = (kt+2)*BK;
    bf16x8 bv[2];
    #pragma unroll
    for (int p=0; p<2; p++){
      bf16x8 av[2];
      #pragma unroll
      for (int jx=0;jx<2;jx++)
        av[jx] = *(const bf16x8*)(Ab + ((p*2+jx)<<10) + laneOff);
      if (p==0){
        #pragma unroll
        for (int jx=0;jx<2;jx++)
          bv[jx] = *(const bf16x8*)(Bb + (jx<<10) + laneOff);
      }
      if (sOK){
        if (p==0) stageA(bstg,k0s);
        else      stageB(bstg,k0s);
      }
      asm volatile("s_barrier" ::: "memory");
      __builtin_amdgcn_s_setprio(1);
      #pragma unroll
      for (int jx=0;jx<2;jx++)
        #pragma unroll
        for (int j2=0;j2<2;j2++)
          acc[p*2+jx][j2] = __builtin_amdgcn_mfma_f32_16x16x32_bf16(av[jx], bv[j2], acc[p*2+jx][j2], 0,0,0);
      __builtin_amdgcn_s_setprio(0);
      if (p==1){
        if (sOK) asm volatile("s_waitcnt vmcnt(2)" ::: "memory");
        else     asm volatile("s_waitcnt vmcnt(0)" ::: "memory");
      }
      asm volatile("s_barrier" ::: "memory");
    }
    bcur = (bcur==2)?0:bcur+1;
  }

  #pragma unroll
  for (int fm=0; fm<4; fm++)
    #pragma unroll
    for (int fn=0; fn<2; fn++)
      #pragma unroll
      for (int i=0; i<4; i++){
        const int r = bm + wm*64 + fm*16 + g*4 + i;
        const int c = bn + wn*32 + fn*16 + q16;
        const size_t idx = (size_t)r*N + c;
        const float vv = X[idx] + acc[fm][fn][i];
        ((bf16_t*)Cout)[idx] = (__bf16)vv;
      }
}

// ---------------- Flash attention v8: 512 thr, KVBLK=128, fast exp2, async-K ----------
// 8 waves x 16 q-rows. Swapped QK^T; in-register softmax over 32 vals/lane;
// P via shfl; K via global_load_lds (pre-swizzled source, 2 passes/tile);
// V reg-staged (2 passes). Indexing verified on-device in round 7 (KVBLK=128 refcheck).
__global__ __launch_bounds__(512, 4) void attn_kernel(
    const bf16_t* __restrict__ QKV, bf16_t* __restrict__ Ctx)
{
  __shared__ __align__(16) bf16_t Ks[2][128*64];     // 32 KB
  __shared__ __align__(16) bf16_t Vs[2][32*4*72];    // 36 KB
  const int tid = threadIdx.x, lane = tid&63, w = tid>>6;
  const int g = lane>>4, q16 = lane&15;
  const int bh = blockIdx.y, b = bh>>4, h = bh&15;
  const int qr0 = blockIdx.x*128 + w*16;
  const size_t tok0 = (size_t)b*SEQL;
  const int ch0 = h*64;

  // Q fragments, pre-scaled by 0.125*log2(e)
  bf16x8 aq[2];
  #pragma unroll
  for (int ks=0; ks<2; ks++){
    bf16x8 t = *(const bf16x8*)(QKV + (tok0+qr0+q16)*QKVN + ch0 + ks*32 + g*8);
    #pragma unroll
    for (int jx=0;jx<8;jx++) t[jx] = (__bf16)((float)t[jx]*0.18033688f);
    aq[ks] = t;
  }

  const int srow = tid>>3, sc8 = (tid&7)*8;
  const bf16_t* kptr_swz = QKV + (tok0+srow)*QKVN + 1024 + ch0 + (sc8 ^ ((srow&7)<<3));
  const bf16_t* vptr = QKV + (tok0+srow)*QKVN + 2048 + ch0 + sc8;
  const int vwoff = ((srow>>2)*4 + (sc8>>4))*72 + (srow&3)*16 + (sc8&15);

  float mrun = -1e30f, lrun = 0.f;
  f32x4 o[4] = {};

  // prologue: stage tile 0 (2 passes of 64 rows), prefetch V of tile 1
  #pragma unroll
  for (int it=0; it<2; it++)
    gload_lds16(kptr_swz + (size_t)(it*64)*QKVN, &Ks[0][tid*8 + it*4096]);
  bf16x8 vreg[2];
  #pragma unroll
  for (int it=0; it<2; it++)
    vreg[it] = *(const bf16x8*)(vptr + (size_t)(it*64)*QKVN);
  #pragma unroll
  for (int it=0; it<2; it++)
    *(bf16x8*)&Vs[0][vwoff + it*4608] = vreg[it];
  #pragma unroll
  for (int it=0; it<2; it++)
    vreg[it] = *(const bf16x8*)(vptr + (size_t)(128 + it*64)*QKVN);

  const int NT = SEQL/128;   // 16
  for (int t=0; t<NT; t++){
    __syncthreads();
    if (t+1 < NT){
      #pragma unroll
      for (int it=0; it<2; it++){
        gload_lds16(kptr_swz + (size_t)((t+1)*128 + it*64)*QKVN, &Ks[(t+1)&1][tid*8 + it*4096]);
        *(bf16x8*)&Vs[(t+1)&1][vwoff + it*4608] = vreg[it];
      }
      if (t+2 < NT){
        #pragma unroll
        for (int it=0; it<2; it++)
          vreg[it] = *(const bf16x8*)(vptr + (size_t)((t+2)*128 + it*64)*QKVN);
      }
    }
    const bf16_t* ksb = Ks[t&1];
    const u32 vs0 = ldsoff(&Vs[t&1][0]);

    // ---- S^T = K (Q*0.125*log2e)^T ----
    f32x4 s[8] = {};
    #pragma unroll
    for (int ks=0; ks<2; ks++){
      #pragma unroll
      for (int fn=0; fn<8; fn++){
        const int r = fn*16 + q16;
        const int ce = ks*32 + g*8;
        bf16x8 bk = *(const bf16x8*)&ksb[r*64 + (ce ^ ((r&7)<<3))];
        s[fn] = __builtin_amdgcn_mfma_f32_16x16x32_bf16(bk, aq[ks], s[fn], 0, 0, 0);
      }
    }

    // ---- in-register online softmax (32 vals/lane, raw v_exp_f32) ----
    float mx = -1e30f;
    #pragma unroll
    for (int fn=0; fn<8; fn++)
      mx = fmaxf(mx, fmaxf(fmaxf(s[fn][0],s[fn][1]), fmaxf(s[fn][2],s[fn][3])));
    mx = fmaxf(mx, __shfl_xor(mx,16));
    mx = fmaxf(mx, __shfl_xor(mx,32));

    if (!__all(mx <= mrun + 11.54f)){      // defer-max, THR = 8*log2e
      const float mnew = fmaxf(mrun, mx);
      const float alpha = __builtin_amdgcn_exp2f(mrun - mnew);
      #pragma unroll
      for (int i=0;i<4;i++){
        const float ai = __shfl(alpha, g*4+i);
        o[0][i]*=ai; o[1][i]*=ai; o[2][i]*=ai; o[3][i]*=ai;
      }
      lrun *= alpha;
      mrun = mnew;
    }

    float rs = 0.f;
    u32 u[8][2];
    #pragma unroll
    for (int fn=0; fn<8; fn++){
      const float e0=__builtin_amdgcn_exp2f(s[fn][0]-mrun);
      const float e1=__builtin_amdgcn_exp2f(s[fn][1]-mrun);
      const float e2=__builtin_amdgcn_exp2f(s[fn][2]-mrun);
      const float e3=__builtin_amdgcn_exp2f(s[fn][3]-mrun);
      rs += (e0+e1)+(e2+e3);
      u[fn][0] = pack2(e0,e1);
      u[fn][1] = pack2(e2,e3);
    }
    rs += __shfl_xor(rs,16);
    rs += __shfl_xor(rs,32);
    lrun += rs;

    // ---- O += P V ----
    #pragma unroll
    for (int ks=0; ks<4; ks++){
      u32x2 vlo[4], vhi[4];
      #pragma unroll
      for (int ne=0; ne<4; ne++){
        const u32 vb = vs0 + (u32)((((ks*8 + 2*g)*4 + ne)*72 + q16)*2);
        vlo[ne] = tr64(vb);
        vhi[ne] = tr64(vb + 576);
      }
      union { u32 wd[4]; bf16x8 v; } pa;
      #pragma unroll
      for (int jj=0; jj<4; jj++){
        const int src = q16 + ((((g&1)<<1) + (jj>>1))<<4);
        const u32 a0 = (u32)__shfl((int)u[2*ks  ][jj&1], src);
        const u32 a1 = (u32)__shfl((int)u[2*ks+1][jj&1], src);
        pa.wd[jj] = (g&2) ? a1 : a0;
      }
      asm volatile("s_waitcnt lgkmcnt(0)" ::: "memory");
      __builtin_amdgcn_sched_barrier(0);
      union { u32x2 u2[2]; bf16x8 v; } cc;
      #pragma unroll
      for (int ne=0; ne<4; ne++){
        cc.u2[0]=vlo[ne]; cc.u2[1]=vhi[ne];
        o[ne] = __builtin_amdgcn_mfma_f32_16x16x32_bf16(pa.v, cc.v, o[ne], 0, 0, 0);
      }
    }
  }

  const float rl = 1.0f/lrun;
  #pragma unroll
  for (int i=0; i<4; i++){
    const float ri = __shfl(rl, g*4+i);
    #pragma unroll
    for (int ne=0; ne<4; ne++){
      const int r = qr0 + g*4 + i;
      Ctx[(tok0+r)*DM + ch0 + ne*16 + q16] = (__bf16)(o[ne][i]*ri);
    }
  }
}

// ---------------- launcher ----------------
extern "C" void kernel_launch(void* const* d_in, const int* in_sizes, int n_in,
                              void* d_out, int out_size, void* d_ws, size_t ws_size,
                              hipStream_t stream)
{
  (void)in_sizes; (void)n_in; (void)out_size; (void)ws_size;
  const float* x  = (const float*)d_in[0];
  const float* wq = (const float*)d_in[1];
  const float* wk = (const float*)d_in[2];
  const float* wv = (const float*)d_in[3];
  const float* wo = (const float*)d_in[4];
  const float* w1 = (const float*)d_in[5];
  const float* w2 = (const float*)d_in[6];
  const float* g1 = (const float*)d_in[7];
  const float* b1 = (const float*)d_in[8];
  const float* g2 = (const float*)d_in[9];
  const float* b2 = (const float*)d_in[10];
  float* out = (float*)d_out;
  char* ws = (char*)d_ws;
  const size_t MB = 1024ull*1024ull;

  bf16_t* wqkv_b = (bf16_t*)(ws);            // 6 MB  [3072][1024]
  bf16_t* wo_b   = (bf16_t*)(ws + 6*MB);     // 2 MB
  bf16_t* w1_b   = (bf16_t*)(ws + 8*MB);     // 8 MB
  bf16_t* w2_b   = (bf16_t*)(ws + 16*MB);    // 8 MB
  bf16_t* h1     = (bf16_t*)(ws + 24*MB);    // 8 MB
  bf16_t* qkv    = (bf16_t*)(ws + 32*MB);    // 24 MB [4096][3072]
  bf16_t* ctx    = (bf16_t*)(ws + 56*MB);    // 8 MB
  bf16_t* res2b  = (bf16_t*)(ws + 64*MB);    // 8 MB (bf16 x+attn residual)
  bf16_t* h2     = h1;                       // alias: h1 dead after QKV GEMM
  bf16_t* ffm    = (bf16_t*)(ws + 32*MB);    // 32 MB, alias qkv+ctx (dead by then)
  // FF2 split-K partials (all regions dead by FF2 time):
  bf16_t* p0     = (bf16_t*)(ws);            // 8 MB (wqkv_b dead)
  bf16_t* p1     = (bf16_t*)(ws + 8*MB);     // 8 MB (w1_b dead after FF1)
  bf16_t* p2     = (bf16_t*)(ws + 24*MB);    // 8 MB (h1/h2 dead after FF1)
  bf16_t* p3     = (bf16_t*)(ws + 64*MB);    // 8 MB (res2b dead after LN2)

  prep_kernel<<<16384, 256, 0, stream>>>(wq, wk, wv, wo, w1, w2, x, g1, b1,
                                         wqkv_b, wo_b, w1_b, w2_b, h1);
  gemm8ph<0><<<dim3(16, 12), 512, 0, stream>>>(h1, wqkv_b, (void*)qkv, (void*)qkv,
                                               (void*)qkv, (void*)qkv, QKVN, 1024, 1024);
  attn_kernel<<<dim3(16, 32), 512, 0, stream>>>(qkv, ctx);
  gemm128<0><<<dim3(32, 8), 512, 0, stream>>>(ctx, wo_b, (void*)res2b, x, 1024, 1024);
  lnb_kernel<<<NTOK, 256, 0, stream>>>(res2b, g2, b2, h2);
  gemm8ph<2><<<dim3(16, 16), 512, 0, stream>>>(h2, w1_b, (void*)ffm, (void*)ffm,
                                               (void*)ffm, (void*)ffm, 4096, 1024, 1024);
  gemm8ph<0><<<dim3(16, 4, 4), 512, 0, stream>>>(ffm, w2_b, (void*)p0, (void*)p1,
                                                 (void*)p2, (void*)p3, 1024, 1024, 4096);
  red4_kernel<<<4096, 256, 0, stream>>>(p0, p1, p2, p3, x, out);
}

// Round 13
// 233.030 us; speedup vs baseline: 1.0915x; 1.0475x over previous
//
#include <hip/hip_runtime.h>
#include <hip/hip_bf16.h>
#include <math.h>

typedef __bf16 bf16_t;
typedef __bf16 bf16x8 __attribute__((ext_vector_type(8)));
typedef __bf16 bf16x4 __attribute__((ext_vector_type(4)));
typedef float f32x4 __attribute__((ext_vector_type(4)));
typedef unsigned int u32;
typedef u32 u32x2 __attribute__((ext_vector_type(2)));

#define DM 1024
#define SEQL 2048
#define NTOK 4096
#define QKVN 3072

__device__ __forceinline__ void gload_lds16(const bf16_t* g, bf16_t* l){
  __builtin_amdgcn_global_load_lds((const __attribute__((address_space(1))) void*)g,
                                   (__attribute__((address_space(3))) void*)l, 16, 0, 0);
}
__device__ __forceinline__ u32 ldsoff(const void* p){
  return (u32)(size_t)(__attribute__((address_space(3))) const void*)p;
}
__device__ __forceinline__ u32x2 tr64(u32 byte_off){
  u32x2 d;
  asm volatile("ds_read_b64_tr_b16 %0, %1" : "=v"(d) : "v"(byte_off));
  return d;
}
__device__ __forceinline__ u32 pack2(float a, float b){
  union{ __bf16 h[2]; u32 w; } z;
  z.h[0]=(__bf16)a; z.h[1]=(__bf16)b; return z.w;
}
// fast GELU: 0.5x(1+tanh(0.79788456(x+0.044715x^3))), tanh via raw v_exp_f32
__device__ __forceinline__ float gelu_fast(float x){
  const float y = 0.79788456f*(x + 0.044715f*x*x*x);
  float a = y*2.885390082f;                 // 2*log2(e)*y
  a = fminf(fmaxf(a, -30.f), 30.f);
  const float t = __builtin_amdgcn_exp2f(a);
  const float th = (t-1.0f)*__builtin_amdgcn_rcpf(t+1.0f);
  return 0.5f*x*(1.0f+th);
}

// ---------------- prep: all weight cvts (12M elems) + LN1, one launch ----------------
__global__ __launch_bounds__(256) void prep_kernel(
    const float* __restrict__ wq, const float* __restrict__ wk,
    const float* __restrict__ wv, const float* __restrict__ wo,
    const float* __restrict__ w1, const float* __restrict__ w2,
    const float* __restrict__ x,  const float* __restrict__ g1,
    const float* __restrict__ b1,
    bf16_t* __restrict__ wqkv_b, bf16_t* __restrict__ wo_b,
    bf16_t* __restrict__ w1_b,   bf16_t* __restrict__ w2_b,
    bf16_t* __restrict__ h1)
{
  __shared__ float red[8];
  const int bid = blockIdx.x;
  const int t = threadIdx.x;
  if (bid < 12288){
    const int flat = (bid*256 + t)*4;
    const int seg = flat >> 20;
    const int off1m = flat & 1048575;
    const float* src; bf16_t* dst;
    if (seg < 3){
      src = (seg==0 ? wq : (seg==1 ? wk : wv)) + off1m;
      dst = wqkv_b + flat;
    } else if (seg == 3){
      src = wo + off1m;  dst = wo_b + off1m;
    } else if (seg < 8){
      src = w1 + (flat - 4*1048576);  dst = w1_b + (flat - 4*1048576);
    } else {
      src = w2 + (flat - 8*1048576);  dst = w2_b + (flat - 8*1048576);
    }
    const float4 v = *(const float4*)src;
    bf16x4 o; o[0]=(__bf16)v.x; o[1]=(__bf16)v.y; o[2]=(__bf16)v.z; o[3]=(__bf16)v.w;
    *(bf16x4*)dst = o;
  } else {
    const int row = bid - 12288;
    const float4 v = *(const float4*)(x + (size_t)row*DM + t*4);
    float s  = v.x+v.y+v.z+v.w;
    float sq = v.x*v.x+v.y*v.y+v.z*v.z+v.w*v.w;
    #pragma unroll
    for (int m=1;m<64;m<<=1){ s += __shfl_xor(s,m); sq += __shfl_xor(sq,m); }
    const int w = t>>6;
    if ((t&63)==0){ red[w]=s; red[4+w]=sq; }
    __syncthreads();
    s  = red[0]+red[1]+red[2]+red[3];
    sq = red[4]+red[5]+red[6]+red[7];
    const float mean = s*(1.f/DM);
    const float var  = sq*(1.f/DM) - mean*mean;
    const float rstd = rsqrtf(var + 1e-5f);
    const float4 gg = *(const float4*)(g1 + t*4);
    const float4 bb = *(const float4*)(b1 + t*4);
    bf16x4 o;
    o[0]=(__bf16)((v.x-mean)*rstd*gg.x+bb.x);
    o[1]=(__bf16)((v.y-mean)*rstd*gg.y+bb.y);
    o[2]=(__bf16)((v.z-mean)*rstd*gg.z+bb.z);
    o[3]=(__bf16)((v.w-mean)*rstd*gg.w+bb.w);
    *(bf16x4*)(h1 + (size_t)row*DM + t*4) = o;
  }
}

// ---------------- LayerNorm (LN2, bf16 input) ----------------
__global__ __launch_bounds__(256) void lnb_kernel(const bf16_t* __restrict__ in,
    const float* __restrict__ g, const float* __restrict__ bta,
    bf16_t* __restrict__ outp)
{
  const int row = blockIdx.x;
  const int t = threadIdx.x;
  const bf16x4 raw = *(const bf16x4*)(in + (size_t)row*DM + t*4);
  float4 v;
  v.x=(float)raw[0]; v.y=(float)raw[1]; v.z=(float)raw[2]; v.w=(float)raw[3];
  float s  = v.x+v.y+v.z+v.w;
  float sq = v.x*v.x+v.y*v.y+v.z*v.z+v.w*v.w;
  #pragma unroll
  for (int m=1;m<64;m<<=1){ s += __shfl_xor(s,m); sq += __shfl_xor(sq,m); }
  __shared__ float red[8];
  const int w = t>>6;
  if ((t&63)==0){ red[w]=s; red[4+w]=sq; }
  __syncthreads();
  s  = red[0]+red[1]+red[2]+red[3];
  sq = red[4]+red[5]+red[6]+red[7];
  const float mean = s*(1.f/DM);
  const float var  = sq*(1.f/DM) - mean*mean;
  const float rstd = rsqrtf(var + 1e-5f);
  const float4 gg = *(const float4*)(g + t*4);
  const float4 bb = *(const float4*)(bta + t*4);
  bf16x4 o;
  o[0]=(__bf16)((v.x-mean)*rstd*gg.x+bb.x);
  o[1]=(__bf16)((v.y-mean)*rstd*gg.y+bb.y);
  o[2]=(__bf16)((v.z-mean)*rstd*gg.z+bb.z);
  o[3]=(__bf16)((v.w-mean)*rstd*gg.w+bb.w);
  *(bf16x4*)(outp + (size_t)row*DM + t*4) = o;
}

// ---------------- final reduce: out = x + sum of 4 bf16 partials ----------------
__global__ __launch_bounds__(256) void red4_kernel(
    const bf16_t* __restrict__ p0, const bf16_t* __restrict__ p1,
    const bf16_t* __restrict__ p2, const bf16_t* __restrict__ p3,
    const float* __restrict__ x, float* __restrict__ outp)
{
  const int i = (blockIdx.x*256 + threadIdx.x)*4;
  const bf16x4 a0 = *(const bf16x4*)(p0 + i);
  const bf16x4 a1 = *(const bf16x4*)(p1 + i);
  const bf16x4 a2 = *(const bf16x4*)(p2 + i);
  const bf16x4 a3 = *(const bf16x4*)(p3 + i);
  const float4 xs = *(const float4*)(x + i);
  float4 o;
  o.x = xs.x + ((float)a0[0]+(float)a1[0]) + ((float)a2[0]+(float)a3[0]);
  o.y = xs.y + ((float)a0[1]+(float)a1[1]) + ((float)a2[1]+(float)a3[1]);
  o.z = xs.z + ((float)a0[2]+(float)a1[2]) + ((float)a2[2]+(float)a3[2]);
  o.w = xs.w + ((float)a0[3]+(float)a1[3]) + ((float)a2[3]+(float)a3[3]);
  *(float4*)(outp + i) = o;
}

// ---------------- 256x256 8-phase GEMM (m201 template port, split-K capable) -----------
template<int EPI>
__global__ __launch_bounds__(512, 2) void gemm8ph(
    const bf16_t* __restrict__ A, const bf16_t* __restrict__ Bw,
    void* __restrict__ c0, void* __restrict__ c1,
    void* __restrict__ c2, void* __restrict__ c3,
    int N, int K, int lda)
{
  __shared__ __align__(16) char ldsb[131072];
  const int tid = threadIdx.x, lane = tid&63, wid = tid>>6;
  const int q16 = lane&15, g = lane>>4;
  const int wm = wid>>2, wn = wid&3;

  const int flat = blockIdx.y*gridDim.x + blockIdx.x;
  const int xcd = flat&7, jj = flat>>3;
  const int NY = gridDim.y;
  const int jdiv = jj/NY, jmod = jj - jdiv*NY;
  const int bm = (xcd*2 + jdiv)*256, bn = jmod*256;
  const int sk = blockIdx.z;
  const int koff = sk*K;
  void* Cout = (sk==0) ? c0 : (sk==1) ? c1 : (sk==2) ? c2 : c3;

  int mloc, kloc;
  {
    const u32 L = tid*16;
    const u32 logical = L ^ (((L>>9)&1)<<5);
    mloc = (int)(logical>>6);
    kloc = (int)((logical&63)>>1);
  }
  const bf16_t* asrc = A  + (size_t)(bm + mloc)*lda + koff + kloc;
  const bf16_t* bsrc = Bw + (size_t)(bn + mloc)*lda + koff + kloc;
  const u32 laneOff = ((u32)(q16*64 + g*16)) ^ ((u32)(q16&8)<<2);

  f32x4 acc[8][4] = {};
  bf16x8 bv[4];

  auto stage = [&](int buf, int kh, int isB, int s){
    const bf16_t* src = isB ? bsrc : asrc;
    #pragma unroll
    for (int h2=0; h2<2; h2++)
      gload_lds16(src + (size_t)(h2*128)*lda + s*64 + kh*32,
                  (bf16_t*)(ldsb + buf*65536 + isB*32768 + kh*16384 + h2*8192 + tid*16));
  };

  stage(0,0,0,0); stage(0,0,1,0); stage(0,1,0,0); stage(0,1,1,0);
  stage(1,0,0,1); stage(1,0,1,1);
  asm volatile("s_waitcnt vmcnt(4)" ::: "memory");
  __builtin_amdgcn_s_barrier();

  const int NSTEP = K>>6;
  const int NIT = NSTEP>>1;

#define PHASE(BUF,KH,MH,DOST,SBUF,SKH,SISB,SSTEP,CK) { \
    bf16x8 av[4]; \
    const char* Ab_ = ldsb + (BUF)*65536 + (KH)*16384 + wm*8192; \
    _Pragma("unroll") for (int jx=0;jx<4;jx++) \
      av[jx] = *(const bf16x8*)(Ab_ + (((MH)*4+jx)<<10) + laneOff); \
    if ((MH)==0){ \
      const char* Bb_ = ldsb + (BUF)*65536 + 32768 + (KH)*16384 + (wn>>1)*8192; \
      _Pragma("unroll") for (int jx=0;jx<4;jx++) \
        bv[jx] = *(const bf16x8*)(Bb_ + ((((wn&1)*4)+jx)<<10) + laneOff); \
    } \
    if (DOST) stage(SBUF,SKH,SISB,SSTEP); \
    asm volatile("s_barrier" ::: "memory"); \
    asm volatile("s_waitcnt lgkmcnt(0)" ::: "memory"); \
    __builtin_amdgcn_s_setprio(1); \
    _Pragma("unroll") for (int jx=0;jx<4;jx++) \
      _Pragma("unroll") for (int j2=0;j2<4;j2++) \
        acc[(MH)*4+jx][j2] = __builtin_amdgcn_mfma_f32_16x16x32_bf16(av[jx], bv[j2], acc[(MH)*4+jx][j2],0,0,0); \
    __builtin_amdgcn_s_setprio(0); \
    if (CK){ if (nl) { asm volatile("s_waitcnt vmcnt(4)" ::: "memory"); } \
             else    { asm volatile("s_waitcnt vmcnt(0)" ::: "memory"); } } \
    asm volatile("s_barrier" ::: "memory"); }

  for (int it=0; it<NIT; it++){
    const int s0 = 2*it, s1 = s0+1;
    const bool nl = (it+1 < NIT);
    PHASE(0,0,0, 1,  1,1,0, s1,   0)
    PHASE(0,0,1, 1,  1,1,1, s1,   0)
    PHASE(0,1,0, nl, 0,0,0, s0+2, 0)
    PHASE(0,1,1, nl, 0,0,1, s0+2, 1)
    PHASE(1,0,0, nl, 0,1,0, s0+2, 0)
    PHASE(1,0,1, nl, 0,1,1, s0+2, 0)
    PHASE(1,1,0, nl, 1,0,0, s1+2, 0)
    PHASE(1,1,1, nl, 1,0,1, s1+2, 1)
  }
#undef PHASE

  #pragma unroll
  for (int fm=0; fm<8; fm++)
    #pragma unroll
    for (int fn=0; fn<4; fn++)
      #pragma unroll
      for (int i=0; i<4; i++){
        const int r = bm + wm*128 + fm*16 + g*4 + i;
        const int c = bn + wn*64 + fn*16 + q16;
        const size_t idx = (size_t)r*N + c;
        const float vv = acc[fm][fn][i];
        if constexpr (EPI==0){
          ((bf16_t*)Cout)[idx] = (__bf16)vv;
        } else {
          ((bf16_t*)Cout)[idx] = (__bf16)gelu_fast(vv);
        }
      }
}

// ---------------- 128x128 phase-split GEMM (WO) --------------------
template<int EPI>
__global__ __launch_bounds__(512, 2) void gemm128(
    const bf16_t* __restrict__ A, const bf16_t* __restrict__ Bw,
    void* __restrict__ Cout, const float* __restrict__ X,
    int N, int K)
{
  constexpr int BK = 32;
  __shared__ __align__(16) char ldsb[3*16384];   // 48 KB
  const int tid = threadIdx.x, lane = tid&63, wid = tid>>6;
  const int q16 = lane&15, g = lane>>4;
  const int wm = wid>>2, wn = wid&3;

  const int flat = blockIdx.y*gridDim.x + blockIdx.x;   // grid 32x8 = 256
  const int xcd = flat&7, j = flat>>3;
  const int bm = ((xcd<<2) + (j>>3))*128, bn = (j&7)*128;

  int mloc, kloc;
  {
    const u32 L = tid*16;
    const u32 logical = L ^ (((L>>9)&1)<<5);
    mloc = (int)(logical>>6);
    kloc = (int)((logical&63)>>1);
  }
  const bf16_t* asrc = A  + (size_t)(bm + mloc)*K + kloc;
  const bf16_t* bsrc = Bw + (size_t)(bn + mloc)*K + kloc;
  const u32 laneOff = ((u32)(q16*64 + g*16)) ^ ((u32)(q16&8)<<2);

  f32x4 acc[4][2] = {};

  auto stageA = [&](int buf, int k0){
    gload_lds16(asrc + k0, (bf16_t*)(ldsb + buf*16384 + tid*16));
  };
  auto stageB = [&](int buf, int k0){
    gload_lds16(bsrc + k0, (bf16_t*)(ldsb + buf*16384 + 8192 + tid*16));
  };

  stageA(0,0); stageB(0,0);
  stageA(1,BK); stageB(1,BK);
  asm volatile("s_waitcnt vmcnt(2)" ::: "memory");
  __builtin_amdgcn_s_barrier();

  const int NT = K/BK;
  int bcur = 0;
  for (int kt=0; kt<NT; kt++){
    const int bstg = (bcur >= 1) ? bcur-1 : bcur+2;
    const char* Ab = ldsb + bcur*16384 + wm*4096;
    const char* Bb = ldsb + bcur*16384 + 8192 + wn*2048;
    const bool sOK = (kt+2 < NT);
    const int k0s = (kt+2)*BK;
    bf16x8 bv[2];
    #pragma unroll
    for (int p=0; p<2; p++){
      bf16x8 av[2];
      #pragma unroll
      for (int jx=0;jx<2;jx++)
        av[jx] = *(const bf16x8*)(Ab + ((p*2+jx)<<10) + laneOff);
      if (p==0){
        #pragma unroll
        for (int jx=0;jx<2;jx++)
          bv[jx] = *(const bf16x8*)(Bb + (jx<<10) + laneOff);
      }
      if (sOK){
        if (p==0) stageA(bstg,k0s);
        else      stageB(bstg,k0s);
      }
      asm volatile("s_barrier" ::: "memory");
      __builtin_amdgcn_s_setprio(1);
      #pragma unroll
      for (int jx=0;jx<2;jx++)
        #pragma unroll
        for (int j2=0;j2<2;j2++)
          acc[p*2+jx][j2] = __builtin_amdgcn_mfma_f32_16x16x32_bf16(av[jx], bv[j2], acc[p*2+jx][j2], 0,0,0);
      __builtin_amdgcn_s_setprio(0);
      if (p==1){
        if (sOK) asm volatile("s_waitcnt vmcnt(2)" ::: "memory");
        else     asm volatile("s_waitcnt vmcnt(0)" ::: "memory");
      }
      asm volatile("s_barrier" ::: "memory");
    }
    bcur = (bcur==2)?0:bcur+1;
  }

  #pragma unroll
  for (int fm=0; fm<4; fm++)
    #pragma unroll
    for (int fn=0; fn<2; fn++)
      #pragma unroll
      for (int i=0; i<4; i++){
        const int r = bm + wm*64 + fm*16 + g*4 + i;
        const int c = bn + wn*32 + fn*16 + q16;
        const size_t idx = (size_t)r*N + c;
        const float vv = X[idx] + acc[fm][fn][i];
        ((bf16_t*)Cout)[idx] = (__bf16)vv;
      }
}

// ---------------- Flash attention v9: v8 + software-pipelined PV tr64 ----------------
// 512 thr, KVBLK=128, fast exp2, async-K. PV: 2-deep A/B tr64 buffers; counted
// lgkmcnt(8) keeps next quarter's tr64 in flight across each MFMA group (T4 micro).
__global__ __launch_bounds__(512, 4) void attn_kernel(
    const bf16_t* __restrict__ QKV, bf16_t* __restrict__ Ctx)
{
  __shared__ __align__(16) bf16_t Ks[2][128*64];     // 32 KB
  __shared__ __align__(16) bf16_t Vs[2][32*4*72];    // 36 KB
  const int tid = threadIdx.x, lane = tid&63, w = tid>>6;
  const int g = lane>>4, q16 = lane&15;
  const int bh = blockIdx.y, b = bh>>4, h = bh&15;
  const int qr0 = blockIdx.x*128 + w*16;
  const size_t tok0 = (size_t)b*SEQL;
  const int ch0 = h*64;

  bf16x8 aq[2];
  #pragma unroll
  for (int ks=0; ks<2; ks++){
    bf16x8 t = *(const bf16x8*)(QKV + (tok0+qr0+q16)*QKVN + ch0 + ks*32 + g*8);
    #pragma unroll
    for (int jx=0;jx<8;jx++) t[jx] = (__bf16)((float)t[jx]*0.18033688f);
    aq[ks] = t;
  }

  const int srow = tid>>3, sc8 = (tid&7)*8;
  const bf16_t* kptr_swz = QKV + (tok0+srow)*QKVN + 1024 + ch0 + (sc8 ^ ((srow&7)<<3));
  const bf16_t* vptr = QKV + (tok0+srow)*QKVN + 2048 + ch0 + sc8;
  const int vwoff = ((srow>>2)*4 + (sc8>>4))*72 + (srow&3)*16 + (sc8&15);

  float mrun = -1e30f, lrun = 0.f;
  f32x4 o[4] = {};

  #pragma unroll
  for (int it=0; it<2; it++)
    gload_lds16(kptr_swz + (size_t)(it*64)*QKVN, &Ks[0][tid*8 + it*4096]);
  bf16x8 vreg[2];
  #pragma unroll
  for (int it=0; it<2; it++)
    vreg[it] = *(const bf16x8*)(vptr + (size_t)(it*64)*QKVN);
  #pragma unroll
  for (int it=0; it<2; it++)
    *(bf16x8*)&Vs[0][vwoff + it*4608] = vreg[it];
  #pragma unroll
  for (int it=0; it<2; it++)
    vreg[it] = *(const bf16x8*)(vptr + (size_t)(128 + it*64)*QKVN);

  const int NT = SEQL/128;   // 16
  for (int t=0; t<NT; t++){
    __syncthreads();
    if (t+1 < NT){
      #pragma unroll
      for (int it=0; it<2; it++){
        gload_lds16(kptr_swz + (size_t)((t+1)*128 + it*64)*QKVN, &Ks[(t+1)&1][tid*8 + it*4096]);
        *(bf16x8*)&Vs[(t+1)&1][vwoff + it*4608] = vreg[it];
      }
      if (t+2 < NT){
        #pragma unroll
        for (int it=0; it<2; it++)
          vreg[it] = *(const bf16x8*)(vptr + (size_t)((t+2)*128 + it*64)*QKVN);
      }
    }
    const bf16_t* ksb = Ks[t&1];
    const u32 vs0 = ldsoff(&Vs[t&1][0]);

    // ---- S^T = K (Q*0.125*log2e)^T ----
    f32x4 s[8] = {};
    #pragma unroll
    for (int ks=0; ks<2; ks++){
      #pragma unroll
      for (int fn=0; fn<8; fn++){
        const int r = fn*16 + q16;
        const int ce = ks*32 + g*8;
        bf16x8 bk = *(const bf16x8*)&ksb[r*64 + (ce ^ ((r&7)<<3))];
        s[fn] = __builtin_amdgcn_mfma_f32_16x16x32_bf16(bk, aq[ks], s[fn], 0, 0, 0);
      }
    }

    // ---- in-register online softmax (32 vals/lane, raw v_exp_f32) ----
    float mx = -1e30f;
    #pragma unroll
    for (int fn=0; fn<8; fn++)
      mx = fmaxf(mx, fmaxf(fmaxf(s[fn][0],s[fn][1]), fmaxf(s[fn][2],s[fn][3])));
    mx = fmaxf(mx, __shfl_xor(mx,16));
    mx = fmaxf(mx, __shfl_xor(mx,32));

    if (!__all(mx <= mrun + 11.54f)){      // defer-max, THR = 8*log2e
      const float mnew = fmaxf(mrun, mx);
      const float alpha = __builtin_amdgcn_exp2f(mrun - mnew);
      #pragma unroll
      for (int i=0;i<4;i++){
        const float ai = __shfl(alpha, g*4+i);
        o[0][i]*=ai; o[1][i]*=ai; o[2][i]*=ai; o[3][i]*=ai;
      }
      lrun *= alpha;
      mrun = mnew;
    }

    float rs = 0.f;
    u32 u[8][2];
    #pragma unroll
    for (int fn=0; fn<8; fn++){
      const float e0=__builtin_amdgcn_exp2f(s[fn][0]-mrun);
      const float e1=__builtin_amdgcn_exp2f(s[fn][1]-mrun);
      const float e2=__builtin_amdgcn_exp2f(s[fn][2]-mrun);
      const float e3=__builtin_amdgcn_exp2f(s[fn][3]-mrun);
      rs += (e0+e1)+(e2+e3);
      u[fn][0] = pack2(e0,e1);
      u[fn][1] = pack2(e2,e3);
    }
    rs += __shfl_xor(rs,16);
    rs += __shfl_xor(rs,32);
    lrun += rs;

    // ---- O += P V  (pipelined tr64: 2-deep A/B buffers, counted lgkmcnt) ----
    {
      u32x2 loA[4], hiA[4], loB[4], hiB[4];
      #pragma unroll
      for (int ne=0; ne<4; ne++){
        const u32 vb = vs0 + (u32)(((2*g*4 + ne)*72 + q16)*2);   // ks=0
        loA[ne] = tr64(vb);
        hiA[ne] = tr64(vb + 576);
      }
      #pragma unroll
      for (int ks=0; ks<4; ks++){
        // build P A-frag for this quarter
        union { u32 wd[4]; bf16x8 v; } pa;
        #pragma unroll
        for (int jj=0; jj<4; jj++){
          const int src = q16 + ((((g&1)<<1) + (jj>>1))<<4);
          const u32 a0 = (u32)__shfl((int)u[2*ks  ][jj&1], src);
          const u32 a1 = (u32)__shfl((int)u[2*ks+1][jj&1], src);
          pa.wd[jj] = (g&2) ? a1 : a0;
        }
        // issue next quarter's tr64 into the other buffer
        if (ks < 3){
          u32x2* nl_ = (ks&1) ? loA : loB;
          u32x2* nh_ = (ks&1) ? hiA : hiB;
          #pragma unroll
          for (int ne=0; ne<4; ne++){
            const u32 vb = vs0 + (u32)(((((ks+1)*8 + 2*g)*4 + ne)*72 + q16)*2);
            nl_[ne] = tr64(vb);
            nh_[ne] = tr64(vb + 576);
          }
          asm volatile("s_waitcnt lgkmcnt(8)" ::: "memory");
        } else {
          asm volatile("s_waitcnt lgkmcnt(0)" ::: "memory");
        }
        __builtin_amdgcn_sched_barrier(0);
        const u32x2* lo = (ks&1) ? loB : loA;
        const u32x2* hi = (ks&1) ? hiB : hiA;
        union { u32x2 u2[2]; bf16x8 v; } cc;
        #pragma unroll
        for (int ne=0; ne<4; ne++){
          cc.u2[0]=lo[ne]; cc.u2[1]=hi[ne];
          o[ne] = __builtin_amdgcn_mfma_f32_16x16x32_bf16(pa.v, cc.v, o[ne], 0, 0, 0);
        }
      }
    }
  }

  const float rl = 1.0f/lrun;
  #pragma unroll
  for (int i=0; i<4; i++){
    const float ri = __shfl(rl, g*4+i);
    #pragma unroll
    for (int ne=0; ne<4; ne++){
      const int r = qr0 + g*4 + i;
      Ctx[(tok0+r)*DM + ch0 + ne*16 + q16] = (__bf16)(o[ne][i]*ri);
    }
  }
}

// ---------------- launcher ----------------
extern "C" void kernel_launch(void* const* d_in, const int* in_sizes, int n_in,
                              void* d_out, int out_size, void* d_ws, size_t ws_size,
                              hipStream_t stream)
{
  (void)in_sizes; (void)n_in; (void)out_size; (void)ws_size;
  const float* x  = (const float*)d_in[0];
  const float* wq = (const float*)d_in[1];
  const float* wk = (const float*)d_in[2];
  const float* wv = (const float*)d_in[3];
  const float* wo = (const float*)d_in[4];
  const float* w1 = (const float*)d_in[5];
  const float* w2 = (const float*)d_in[6];
  const float* g1 = (const float*)d_in[7];
  const float* b1 = (const float*)d_in[8];
  const float* g2 = (const float*)d_in[9];
  const float* b2 = (const float*)d_in[10];
  float* out = (float*)d_out;
  char* ws = (char*)d_ws;
  const size_t MB = 1024ull*1024ull;

  bf16_t* wqkv_b = (bf16_t*)(ws);            // 6 MB  [3072][1024]
  bf16_t* wo_b   = (bf16_t*)(ws + 6*MB);     // 2 MB
  bf16_t* w1_b   = (bf16_t*)(ws + 8*MB);     // 8 MB
  bf16_t* w2_b   = (bf16_t*)(ws + 16*MB);    // 8 MB
  bf16_t* h1     = (bf16_t*)(ws + 24*MB);    // 8 MB
  bf16_t* qkv    = (bf16_t*)(ws + 32*MB);    // 24 MB [4096][3072]
  bf16_t* ctx    = (bf16_t*)(ws + 56*MB);    // 8 MB
  bf16_t* res2b  = (bf16_t*)(ws + 64*MB);    // 8 MB (bf16 x+attn residual)
  bf16_t* h2     = h1;                       // alias: h1 dead after QKV GEMM
  bf16_t* ffm    = (bf16_t*)(ws + 32*MB);    // 32 MB, alias qkv+ctx (dead by then)
  bf16_t* p0     = (bf16_t*)(ws);            // 8 MB (wqkv_b dead)
  bf16_t* p1     = (bf16_t*)(ws + 8*MB);     // 8 MB (w1_b dead after FF1)
  bf16_t* p2     = (bf16_t*)(ws + 24*MB);    // 8 MB (h1/h2 dead after FF1)
  bf16_t* p3     = (bf16_t*)(ws + 64*MB);    // 8 MB (res2b dead after LN2)

  prep_kernel<<<16384, 256, 0, stream>>>(wq, wk, wv, wo, w1, w2, x, g1, b1,
                                         wqkv_b, wo_b, w1_b, w2_b, h1);
  gemm8ph<0><<<dim3(16, 12), 512, 0, stream>>>(h1, wqkv_b, (void*)qkv, (void*)qkv,
                                               (void*)qkv, (void*)qkv, QKVN, 1024, 1024);
  attn_kernel<<<dim3(16, 32), 512, 0, stream>>>(qkv, ctx);
  gemm128<0><<<dim3(32, 8), 512, 0, stream>>>(ctx, wo_b, (void*)res2b, x, 1024, 1024);
  lnb_kernel<<<NTOK, 256, 0, stream>>>(res2b, g2, b2, h2);
  gemm8ph<2><<<dim3(16, 16), 512, 0, stream>>>(h2, w1_b, (void*)ffm, (void*)ffm,
                                               (void*)ffm, (void*)ffm, 4096, 1024, 1024);
  gemm8ph<0><<<dim3(16, 4, 4), 512, 0, stream>>>(ffm, w2_b, (void*)p0, (void*)p1,
                                                 (void*)p2, (void*)p3, 1024, 1024, 4096);
  red4_kernel<<<4096, 256, 0, stream>>>(p0, p1, p2, p3, x, out);
}

// Round 14
// 231.965 us; speedup vs baseline: 1.0965x; 1.0046x over previous
//
#include <hip/hip_runtime.h>
#include <hip/hip_bf16.h>
#include <math.h>

typedef __bf16 bf16_t;
typedef __bf16 bf16x8 __attribute__((ext_vector_type(8)));
typedef __bf16 bf16x4 __attribute__((ext_vector_type(4)));
typedef float f32x4 __attribute__((ext_vector_type(4)));
typedef unsigned int u32;
typedef u32 u32x2 __attribute__((ext_vector_type(2)));

#define DM 1024
#define SEQL 2048
#define NTOK 4096
#define QKVN 3072

__device__ __forceinline__ void gload_lds16(const bf16_t* g, bf16_t* l){
  __builtin_amdgcn_global_load_lds((const __attribute__((address_space(1))) void*)g,
                                   (__attribute__((address_space(3))) void*)l, 16, 0, 0);
}
__device__ __forceinline__ u32 ldsoff(const void* p){
  return (u32)(size_t)(__attribute__((address_space(3))) const void*)p;
}
__device__ __forceinline__ u32x2 tr64(u32 byte_off){
  u32x2 d;
  asm volatile("ds_read_b64_tr_b16 %0, %1" : "=v"(d) : "v"(byte_off));
  return d;
}
__device__ __forceinline__ u32 pack2(float a, float b){
  union{ __bf16 h[2]; u32 w; } z;
  z.h[0]=(__bf16)a; z.h[1]=(__bf16)b; return z.w;
}
// fast GELU: 0.5x(1+tanh(0.79788456(x+0.044715x^3))), tanh via raw v_exp_f32
__device__ __forceinline__ float gelu_fast(float x){
  const float y = 0.79788456f*(x + 0.044715f*x*x*x);
  float a = y*2.885390082f;                 // 2*log2(e)*y
  a = fminf(fmaxf(a, -30.f), 30.f);
  const float t = __builtin_amdgcn_exp2f(a);
  const float th = (t-1.0f)*__builtin_amdgcn_rcpf(t+1.0f);
  return 0.5f*x*(1.0f+th);
}

// ---------------- prep: all weight cvts (12M elems) + LN1, one launch ----------------
__global__ __launch_bounds__(256) void prep_kernel(
    const float* __restrict__ wq, const float* __restrict__ wk,
    const float* __restrict__ wv, const float* __restrict__ wo,
    const float* __restrict__ w1, const float* __restrict__ w2,
    const float* __restrict__ x,  const float* __restrict__ g1,
    const float* __restrict__ b1,
    bf16_t* __restrict__ wqkv_b, bf16_t* __restrict__ wo_b,
    bf16_t* __restrict__ w1_b,   bf16_t* __restrict__ w2_b,
    bf16_t* __restrict__ h1)
{
  __shared__ float red[8];
  const int bid = blockIdx.x;
  const int t = threadIdx.x;
  if (bid < 12288){
    const int flat = (bid*256 + t)*4;
    const int seg = flat >> 20;
    const int off1m = flat & 1048575;
    const float* src; bf16_t* dst;
    if (seg < 3){
      src = (seg==0 ? wq : (seg==1 ? wk : wv)) + off1m;
      dst = wqkv_b + flat;
    } else if (seg == 3){
      src = wo + off1m;  dst = wo_b + off1m;
    } else if (seg < 8){
      src = w1 + (flat - 4*1048576);  dst = w1_b + (flat - 4*1048576);
    } else {
      src = w2 + (flat - 8*1048576);  dst = w2_b + (flat - 8*1048576);
    }
    const float4 v = *(const float4*)src;
    bf16x4 o; o[0]=(__bf16)v.x; o[1]=(__bf16)v.y; o[2]=(__bf16)v.z; o[3]=(__bf16)v.w;
    *(bf16x4*)dst = o;
  } else {
    const int row = bid - 12288;
    const float4 v = *(const float4*)(x + (size_t)row*DM + t*4);
    float s  = v.x+v.y+v.z+v.w;
    float sq = v.x*v.x+v.y*v.y+v.z*v.z+v.w*v.w;
    #pragma unroll
    for (int m=1;m<64;m<<=1){ s += __shfl_xor(s,m); sq += __shfl_xor(sq,m); }
    const int w = t>>6;
    if ((t&63)==0){ red[w]=s; red[4+w]=sq; }
    __syncthreads();
    s  = red[0]+red[1]+red[2]+red[3];
    sq = red[4]+red[5]+red[6]+red[7];
    const float mean = s*(1.f/DM);
    const float var  = sq*(1.f/DM) - mean*mean;
    const float rstd = rsqrtf(var + 1e-5f);
    const float4 gg = *(const float4*)(g1 + t*4);
    const float4 bb = *(const float4*)(b1 + t*4);
    bf16x4 o;
    o[0]=(__bf16)((v.x-mean)*rstd*gg.x+bb.x);
    o[1]=(__bf16)((v.y-mean)*rstd*gg.y+bb.y);
    o[2]=(__bf16)((v.z-mean)*rstd*gg.z+bb.z);
    o[3]=(__bf16)((v.w-mean)*rstd*gg.w+bb.w);
    *(bf16x4*)(h1 + (size_t)row*DM + t*4) = o;
  }
}

// ---------------- LayerNorm (LN2, bf16 input) ----------------
__global__ __launch_bounds__(256) void lnb_kernel(const bf16_t* __restrict__ in,
    const float* __restrict__ g, const float* __restrict__ bta,
    bf16_t* __restrict__ outp)
{
  const int row = blockIdx.x;
  const int t = threadIdx.x;
  const bf16x4 raw = *(const bf16x4*)(in + (size_t)row*DM + t*4);
  float4 v;
  v.x=(float)raw[0]; v.y=(float)raw[1]; v.z=(float)raw[2]; v.w=(float)raw[3];
  float s  = v.x+v.y+v.z+v.w;
  float sq = v.x*v.x+v.y*v.y+v.z*v.z+v.w*v.w;
  #pragma unroll
  for (int m=1;m<64;m<<=1){ s += __shfl_xor(s,m); sq += __shfl_xor(sq,m); }
  __shared__ float red[8];
  const int w = t>>6;
  if ((t&63)==0){ red[w]=s; red[4+w]=sq; }
  __syncthreads();
  s  = red[0]+red[1]+red[2]+red[3];
  sq = red[4]+red[5]+red[6]+red[7];
  const float mean = s*(1.f/DM);
  const float var  = sq*(1.f/DM) - mean*mean;
  const float rstd = rsqrtf(var + 1e-5f);
  const float4 gg = *(const float4*)(g + t*4);
  const float4 bb = *(const float4*)(bta + t*4);
  bf16x4 o;
  o[0]=(__bf16)((v.x-mean)*rstd*gg.x+bb.x);
  o[1]=(__bf16)((v.y-mean)*rstd*gg.y+bb.y);
  o[2]=(__bf16)((v.z-mean)*rstd*gg.z+bb.z);
  o[3]=(__bf16)((v.w-mean)*rstd*gg.w+bb.w);
  *(bf16x4*)(outp + (size_t)row*DM + t*4) = o;
}

// ---------------- final reduce: out = x + sum of 4 bf16 partials (8 elems/thread) -------
__global__ __launch_bounds__(256) void red4_kernel(
    const bf16_t* __restrict__ p0, const bf16_t* __restrict__ p1,
    const bf16_t* __restrict__ p2, const bf16_t* __restrict__ p3,
    const float* __restrict__ x, float* __restrict__ outp)
{
  const int i = (blockIdx.x*256 + threadIdx.x)*8;
  const bf16x8 a0 = *(const bf16x8*)(p0 + i);
  const bf16x8 a1 = *(const bf16x8*)(p1 + i);
  const bf16x8 a2 = *(const bf16x8*)(p2 + i);
  const bf16x8 a3 = *(const bf16x8*)(p3 + i);
  #pragma unroll
  for (int h=0; h<2; h++){
    const float4 xs = *(const float4*)(x + i + h*4);
    float4 o;
    o.x = xs.x + ((float)a0[h*4+0]+(float)a1[h*4+0]) + ((float)a2[h*4+0]+(float)a3[h*4+0]);
    o.y = xs.y + ((float)a0[h*4+1]+(float)a1[h*4+1]) + ((float)a2[h*4+1]+(float)a3[h*4+1]);
    o.z = xs.z + ((float)a0[h*4+2]+(float)a1[h*4+2]) + ((float)a2[h*4+2]+(float)a3[h*4+2]);
    o.w = xs.w + ((float)a0[h*4+3]+(float)a1[h*4+3]) + ((float)a2[h*4+3]+(float)a3[h*4+3]);
    *(float4*)(outp + i + h*4) = o;
  }
}

// ---------------- 256x256 8-phase GEMM (m201 template port, split-K capable) -----------
template<int EPI>
__global__ __launch_bounds__(512, 2) void gemm8ph(
    const bf16_t* __restrict__ A, const bf16_t* __restrict__ Bw,
    void* __restrict__ c0, void* __restrict__ c1,
    void* __restrict__ c2, void* __restrict__ c3,
    int N, int K, int lda)
{
  __shared__ __align__(16) char ldsb[131072];
  const int tid = threadIdx.x, lane = tid&63, wid = tid>>6;
  const int q16 = lane&15, g = lane>>4;
  const int wm = wid>>2, wn = wid&3;

  const int flat = blockIdx.y*gridDim.x + blockIdx.x;
  const int xcd = flat&7, jj = flat>>3;
  const int NY = gridDim.y;
  const int jdiv = jj/NY, jmod = jj - jdiv*NY;
  const int bm = (xcd*2 + jdiv)*256, bn = jmod*256;
  const int sk = blockIdx.z;
  const int koff = sk*K;
  void* Cout = (sk==0) ? c0 : (sk==1) ? c1 : (sk==2) ? c2 : c3;

  int mloc, kloc;
  {
    const u32 L = tid*16;
    const u32 logical = L ^ (((L>>9)&1)<<5);
    mloc = (int)(logical>>6);
    kloc = (int)((logical&63)>>1);
  }
  const bf16_t* asrc = A  + (size_t)(bm + mloc)*lda + koff + kloc;
  const bf16_t* bsrc = Bw + (size_t)(bn + mloc)*lda + koff + kloc;
  const u32 laneOff = ((u32)(q16*64 + g*16)) ^ ((u32)(q16&8)<<2);

  f32x4 acc[8][4] = {};
  bf16x8 bv[4];

  auto stage = [&](int buf, int kh, int isB, int s){
    const bf16_t* src = isB ? bsrc : asrc;
    #pragma unroll
    for (int h2=0; h2<2; h2++)
      gload_lds16(src + (size_t)(h2*128)*lda + s*64 + kh*32,
                  (bf16_t*)(ldsb + buf*65536 + isB*32768 + kh*16384 + h2*8192 + tid*16));
  };

  stage(0,0,0,0); stage(0,0,1,0); stage(0,1,0,0); stage(0,1,1,0);
  stage(1,0,0,1); stage(1,0,1,1);
  asm volatile("s_waitcnt vmcnt(4)" ::: "memory");
  __builtin_amdgcn_s_barrier();

  const int NSTEP = K>>6;
  const int NIT = NSTEP>>1;

#define PHASE(BUF,KH,MH,DOST,SBUF,SKH,SISB,SSTEP,CK) { \
    bf16x8 av[4]; \
    const char* Ab_ = ldsb + (BUF)*65536 + (KH)*16384 + wm*8192; \
    _Pragma("unroll") for (int jx=0;jx<4;jx++) \
      av[jx] = *(const bf16x8*)(Ab_ + (((MH)*4+jx)<<10) + laneOff); \
    if ((MH)==0){ \
      const char* Bb_ = ldsb + (BUF)*65536 + 32768 + (KH)*16384 + (wn>>1)*8192; \
      _Pragma("unroll") for (int jx=0;jx<4;jx++) \
        bv[jx] = *(const bf16x8*)(Bb_ + ((((wn&1)*4)+jx)<<10) + laneOff); \
    } \
    if (DOST) stage(SBUF,SKH,SISB,SSTEP); \
    asm volatile("s_barrier" ::: "memory"); \
    asm volatile("s_waitcnt lgkmcnt(0)" ::: "memory"); \
    __builtin_amdgcn_s_setprio(1); \
    _Pragma("unroll") for (int jx=0;jx<4;jx++) \
      _Pragma("unroll") for (int j2=0;j2<4;j2++) \
        acc[(MH)*4+jx][j2] = __builtin_amdgcn_mfma_f32_16x16x32_bf16(av[jx], bv[j2], acc[(MH)*4+jx][j2],0,0,0); \
    __builtin_amdgcn_s_setprio(0); \
    if (CK){ if (nl) { asm volatile("s_waitcnt vmcnt(4)" ::: "memory"); } \
             else    { asm volatile("s_waitcnt vmcnt(0)" ::: "memory"); } } \
    asm volatile("s_barrier" ::: "memory"); }

  for (int it=0; it<NIT; it++){
    const int s0 = 2*it, s1 = s0+1;
    const bool nl = (it+1 < NIT);
    PHASE(0,0,0, 1,  1,1,0, s1,   0)
    PHASE(0,0,1, 1,  1,1,1, s1,   0)
    PHASE(0,1,0, nl, 0,0,0, s0+2, 0)
    PHASE(0,1,1, nl, 0,0,1, s0+2, 1)
    PHASE(1,0,0, nl, 0,1,0, s0+2, 0)
    PHASE(1,0,1, nl, 0,1,1, s0+2, 0)
    PHASE(1,1,0, nl, 1,0,0, s1+2, 0)
    PHASE(1,1,1, nl, 1,0,1, s1+2, 1)
  }
#undef PHASE

  #pragma unroll
  for (int fm=0; fm<8; fm++)
    #pragma unroll
    for (int fn=0; fn<4; fn++)
      #pragma unroll
      for (int i=0; i<4; i++){
        const int r = bm + wm*128 + fm*16 + g*4 + i;
        const int c = bn + wn*64 + fn*16 + q16;
        const size_t idx = (size_t)r*N + c;
        const float vv = acc[fm][fn][i];
        if constexpr (EPI==0){
          ((bf16_t*)Cout)[idx] = (__bf16)vv;
        } else {
          ((bf16_t*)Cout)[idx] = (__bf16)gelu_fast(vv);
        }
      }
}

// ---------------- 128x128 phase-split GEMM (WO) --------------------
template<int EPI>
__global__ __launch_bounds__(512, 2) void gemm128(
    const bf16_t* __restrict__ A, const bf16_t* __restrict__ Bw,
    void* __restrict__ Cout, const float* __restrict__ X,
    int N, int K)
{
  constexpr int BK = 32;
  __shared__ __align__(16) char ldsb[3*16384];   // 48 KB
  const int tid = threadIdx.x, lane = tid&63, wid = tid>>6;
  const int q16 = lane&15, g = lane>>4;
  const int wm = wid>>2, wn = wid&3;

  const int flat = blockIdx.y*gridDim.x + blockIdx.x;   // grid 32x8 = 256
  const int xcd = flat&7, j = flat>>3;
  const int bm = ((xcd<<2) + (j>>3))*128, bn = (j&7)*128;

  int mloc, kloc;
  {
    const u32 L = tid*16;
    const u32 logical = L ^ (((L>>9)&1)<<5);
    mloc = (int)(logical>>6);
    kloc = (int)((logical&63)>>1);
  }
  const bf16_t* asrc = A  + (size_t)(bm + mloc)*K + kloc;
  const bf16_t* bsrc = Bw + (size_t)(bn + mloc)*K + kloc;
  const u32 laneOff = ((u32)(q16*64 + g*16)) ^ ((u32)(q16&8)<<2);

  f32x4 acc[4][2] = {};

  auto stageA = [&](int buf, int k0){
    gload_lds16(asrc + k0, (bf16_t*)(ldsb + buf*16384 + tid*16));
  };
  auto stageB = [&](int buf, int k0){
    gload_lds16(bsrc + k0, (bf16_t*)(ldsb + buf*16384 + 8192 + tid*16));
  };

  stageA(0,0); stageB(0,0);
  stageA(1,BK); stageB(1,BK);
  asm volatile("s_waitcnt vmcnt(2)" ::: "memory");
  __builtin_amdgcn_s_barrier();

  const int NT = K/BK;
  int bcur = 0;
  for (int kt=0; kt<NT; kt++){
    const int bstg = (bcur >= 1) ? bcur-1 : bcur+2;
    const char* Ab = ldsb + bcur*16384 + wm*4096;
    const char* Bb = ldsb + bcur*16384 + 8192 + wn*2048;
    const bool sOK = (kt+2 < NT);
    const int k0s = (kt+2)*BK;
    bf16x8 bv[2];
    #pragma unroll
    for (int p=0; p<2; p++){
      bf16x8 av[2];
      #pragma unroll
      for (int jx=0;jx<2;jx++)
        av[jx] = *(const bf16x8*)(Ab + ((p*2+jx)<<10) + laneOff);
      if (p==0){
        #pragma unroll
        for (int jx=0;jx<2;jx++)
          bv[jx] = *(const bf16x8*)(Bb + (jx<<10) + laneOff);
      }
      if (sOK){
        if (p==0) stageA(bstg,k0s);
        else      stageB(bstg,k0s);
      }
      asm volatile("s_barrier" ::: "memory");
      __builtin_amdgcn_s_setprio(1);
      #pragma unroll
      for (int jx=0;jx<2;jx++)
        #pragma unroll
        for (int j2=0;j2<2;j2++)
          acc[p*2+jx][j2] = __builtin_amdgcn_mfma_f32_16x16x32_bf16(av[jx], bv[j2], acc[p*2+jx][j2], 0,0,0);
      __builtin_amdgcn_s_setprio(0);
      if (p==1){
        if (sOK) asm volatile("s_waitcnt vmcnt(2)" ::: "memory");
        else     asm volatile("s_waitcnt vmcnt(0)" ::: "memory");
      }
      asm volatile("s_barrier" ::: "memory");
    }
    bcur = (bcur==2)?0:bcur+1;
  }

  #pragma unroll
  for (int fm=0; fm<4; fm++)
    #pragma unroll
    for (int fn=0; fn<2; fn++)
      #pragma unroll
      for (int i=0; i<4; i++){
        const int r = bm + wm*64 + fm*16 + g*4 + i;
        const int c = bn + wn*32 + fn*16 + q16;
        const size_t idx = (size_t)r*N + c;
        const float vv = X[idx] + acc[fm][fn][i];
        ((bf16_t*)Cout)[idx] = (__bf16)vv;
      }
}

// ---------------- Flash attention v10: v9 + T5 setprio + T17 max3 ----------------
__global__ __launch_bounds__(512, 4) void attn_kernel(
    const bf16_t* __restrict__ QKV, bf16_t* __restrict__ Ctx)
{
  __shared__ __align__(16) bf16_t Ks[2][128*64];     // 32 KB
  __shared__ __align__(16) bf16_t Vs[2][32*4*72];    // 36 KB
  const int tid = threadIdx.x, lane = tid&63, w = tid>>6;
  const int g = lane>>4, q16 = lane&15;
  const int bh = blockIdx.y, b = bh>>4, h = bh&15;
  const int qr0 = blockIdx.x*128 + w*16;
  const size_t tok0 = (size_t)b*SEQL;
  const int ch0 = h*64;

  bf16x8 aq[2];
  #pragma unroll
  for (int ks=0; ks<2; ks++){
    bf16x8 t = *(const bf16x8*)(QKV + (tok0+qr0+q16)*QKVN + ch0 + ks*32 + g*8);
    #pragma unroll
    for (int jx=0;jx<8;jx++) t[jx] = (__bf16)((float)t[jx]*0.18033688f);
    aq[ks] = t;
  }

  const int srow = tid>>3, sc8 = (tid&7)*8;
  const bf16_t* kptr_swz = QKV + (tok0+srow)*QKVN + 1024 + ch0 + (sc8 ^ ((srow&7)<<3));
  const bf16_t* vptr = QKV + (tok0+srow)*QKVN + 2048 + ch0 + sc8;
  const int vwoff = ((srow>>2)*4 + (sc8>>4))*72 + (srow&3)*16 + (sc8&15);

  float mrun = -1e30f, lrun = 0.f;
  f32x4 o[4] = {};

  #pragma unroll
  for (int it=0; it<2; it++)
    gload_lds16(kptr_swz + (size_t)(it*64)*QKVN, &Ks[0][tid*8 + it*4096]);
  bf16x8 vreg[2];
  #pragma unroll
  for (int it=0; it<2; it++)
    vreg[it] = *(const bf16x8*)(vptr + (size_t)(it*64)*QKVN);
  #pragma unroll
  for (int it=0; it<2; it++)
    *(bf16x8*)&Vs[0][vwoff + it*4608] = vreg[it];
  #pragma unroll
  for (int it=0; it<2; it++)
    vreg[it] = *(const bf16x8*)(vptr + (size_t)(128 + it*64)*QKVN);

  const int NT = SEQL/128;   // 16
  for (int t=0; t<NT; t++){
    __syncthreads();
    if (t+1 < NT){
      #pragma unroll
      for (int it=0; it<2; it++){
        gload_lds16(kptr_swz + (size_t)((t+1)*128 + it*64)*QKVN, &Ks[(t+1)&1][tid*8 + it*4096]);
        *(bf16x8*)&Vs[(t+1)&1][vwoff + it*4608] = vreg[it];
      }
      if (t+2 < NT){
        #pragma unroll
        for (int it=0; it<2; it++)
          vreg[it] = *(const bf16x8*)(vptr + (size_t)((t+2)*128 + it*64)*QKVN);
      }
    }
    const bf16_t* ksb = Ks[t&1];
    const u32 vs0 = ldsoff(&Vs[t&1][0]);

    // ---- S^T = K (Q*0.125*log2e)^T  [T5: setprio around MFMA cluster] ----
    f32x4 s[8] = {};
    __builtin_amdgcn_s_setprio(1);
    #pragma unroll
    for (int ks=0; ks<2; ks++){
      #pragma unroll
      for (int fn=0; fn<8; fn++){
        const int r = fn*16 + q16;
        const int ce = ks*32 + g*8;
        bf16x8 bk = *(const bf16x8*)&ksb[r*64 + (ce ^ ((r&7)<<3))];
        s[fn] = __builtin_amdgcn_mfma_f32_16x16x32_bf16(bk, aq[ks], s[fn], 0, 0, 0);
      }
    }
    __builtin_amdgcn_s_setprio(0);

    // ---- in-register online softmax (max3 chains, raw v_exp_f32) ----
    float mx = -1e30f;
    #pragma unroll
    for (int fn=0; fn<8; fn++){
      const float a = fmaxf(fmaxf(s[fn][0], s[fn][1]), s[fn][2]);   // v_max3
      mx = fmaxf(fmaxf(mx, a), s[fn][3]);                            // v_max3
    }
    mx = fmaxf(mx, __shfl_xor(mx,16));
    mx = fmaxf(mx, __shfl_xor(mx,32));

    if (!__all(mx <= mrun + 11.54f)){      // defer-max, THR = 8*log2e
      const float mnew = fmaxf(mrun, mx);
      const float alpha = __builtin_amdgcn_exp2f(mrun - mnew);
      #pragma unroll
      for (int i=0;i<4;i++){
        const float ai = __shfl(alpha, g*4+i);
        o[0][i]*=ai; o[1][i]*=ai; o[2][i]*=ai; o[3][i]*=ai;
      }
      lrun *= alpha;
      mrun = mnew;
    }

    float rs = 0.f;
    u32 u[8][2];
    #pragma unroll
    for (int fn=0; fn<8; fn++){
      const float e0=__builtin_amdgcn_exp2f(s[fn][0]-mrun);
      const float e1=__builtin_amdgcn_exp2f(s[fn][1]-mrun);
      const float e2=__builtin_amdgcn_exp2f(s[fn][2]-mrun);
      const float e3=__builtin_amdgcn_exp2f(s[fn][3]-mrun);
      rs += (e0+e1)+(e2+e3);
      u[fn][0] = pack2(e0,e1);
      u[fn][1] = pack2(e2,e3);
    }
    rs += __shfl_xor(rs,16);
    rs += __shfl_xor(rs,32);
    lrun += rs;

    // ---- O += P V  (pipelined tr64; T5 setprio around each MFMA group) ----
    {
      u32x2 loA[4], hiA[4], loB[4], hiB[4];
      #pragma unroll
      for (int ne=0; ne<4; ne++){
        const u32 vb = vs0 + (u32)(((2*g*4 + ne)*72 + q16)*2);   // ks=0
        loA[ne] = tr64(vb);
        hiA[ne] = tr64(vb + 576);
      }
      #pragma unroll
      for (int ks=0; ks<4; ks++){
        union { u32 wd[4]; bf16x8 v; } pa;
        #pragma unroll
        for (int jj=0; jj<4; jj++){
          const int src = q16 + ((((g&1)<<1) + (jj>>1))<<4);
          const u32 a0 = (u32)__shfl((int)u[2*ks  ][jj&1], src);
          const u32 a1 = (u32)__shfl((int)u[2*ks+1][jj&1], src);
          pa.wd[jj] = (g&2) ? a1 : a0;
        }
        if (ks < 3){
          u32x2* nl_ = (ks&1) ? loA : loB;
          u32x2* nh_ = (ks&1) ? hiA : hiB;
          #pragma unroll
          for (int ne=0; ne<4; ne++){
            const u32 vb = vs0 + (u32)(((((ks+1)*8 + 2*g)*4 + ne)*72 + q16)*2);
            nl_[ne] = tr64(vb);
            nh_[ne] = tr64(vb + 576);
          }
          asm volatile("s_waitcnt lgkmcnt(8)" ::: "memory");
        } else {
          asm volatile("s_waitcnt lgkmcnt(0)" ::: "memory");
        }
        __builtin_amdgcn_sched_barrier(0);
        const u32x2* lo = (ks&1) ? loB : loA;
        const u32x2* hi = (ks&1) ? hiB : hiA;
        union { u32x2 u2[2]; bf16x8 v; } cc;
        __builtin_amdgcn_s_setprio(1);
        #pragma unroll
        for (int ne=0; ne<4; ne++){
          cc.u2[0]=lo[ne]; cc.u2[1]=hi[ne];
          o[ne] = __builtin_amdgcn_mfma_f32_16x16x32_bf16(pa.v, cc.v, o[ne], 0, 0, 0);
        }
        __builtin_amdgcn_s_setprio(0);
      }
    }
  }

  const float rl = 1.0f/lrun;
  #pragma unroll
  for (int i=0; i<4; i++){
    const float ri = __shfl(rl, g*4+i);
    #pragma unroll
    for (int ne=0; ne<4; ne++){
      const int r = qr0 + g*4 + i;
      Ctx[(tok0+r)*DM + ch0 + ne*16 + q16] = (__bf16)(o[ne][i]*ri);
    }
  }
}

// ---------------- launcher ----------------
extern "C" void kernel_launch(void* const* d_in, const int* in_sizes, int n_in,
                              void* d_out, int out_size, void* d_ws, size_t ws_size,
                              hipStream_t stream)
{
  (void)in_sizes; (void)n_in; (void)out_size; (void)ws_size;
  const float* x  = (const float*)d_in[0];
  const float* wq = (const float*)d_in[1];
  const float* wk = (const float*)d_in[2];
  const float* wv = (const float*)d_in[3];
  const float* wo = (const float*)d_in[4];
  const float* w1 = (const float*)d_in[5];
  const float* w2 = (const float*)d_in[6];
  const float* g1 = (const float*)d_in[7];
  const float* b1 = (const float*)d_in[8];
  const float* g2 = (const float*)d_in[9];
  const float* b2 = (const float*)d_in[10];
  float* out = (float*)d_out;
  char* ws = (char*)d_ws;
  const size_t MB = 1024ull*1024ull;

  bf16_t* wqkv_b = (bf16_t*)(ws);            // 6 MB  [3072][1024]
  bf16_t* wo_b   = (bf16_t*)(ws + 6*MB);     // 2 MB
  bf16_t* w1_b   = (bf16_t*)(ws + 8*MB);     // 8 MB
  bf16_t* w2_b   = (bf16_t*)(ws + 16*MB);    // 8 MB
  bf16_t* h1     = (bf16_t*)(ws + 24*MB);    // 8 MB
  bf16_t* qkv    = (bf16_t*)(ws + 32*MB);    // 24 MB [4096][3072]
  bf16_t* ctx    = (bf16_t*)(ws + 56*MB);    // 8 MB
  bf16_t* res2b  = (bf16_t*)(ws + 64*MB);    // 8 MB (bf16 x+attn residual)
  bf16_t* h2     = h1;                       // alias: h1 dead after QKV GEMM
  bf16_t* ffm    = (bf16_t*)(ws + 32*MB);    // 32 MB, alias qkv+ctx (dead by then)
  bf16_t* p0     = (bf16_t*)(ws);            // 8 MB (wqkv_b dead)
  bf16_t* p1     = (bf16_t*)(ws + 8*MB);     // 8 MB (w1_b dead after FF1)
  bf16_t* p2     = (bf16_t*)(ws + 24*MB);    // 8 MB (h1/h2 dead after FF1)
  bf16_t* p3     = (bf16_t*)(ws + 64*MB);    // 8 MB (res2b dead after LN2)

  prep_kernel<<<16384, 256, 0, stream>>>(wq, wk, wv, wo, w1, w2, x, g1, b1,
                                         wqkv_b, wo_b, w1_b, w2_b, h1);
  gemm8ph<0><<<dim3(16, 12), 512, 0, stream>>>(h1, wqkv_b, (void*)qkv, (void*)qkv,
                                               (void*)qkv, (void*)qkv, QKVN, 1024, 1024);
  attn_kernel<<<dim3(16, 32), 512, 0, stream>>>(qkv, ctx);
  gemm128<0><<<dim3(32, 8), 512, 0, stream>>>(ctx, wo_b, (void*)res2b, x, 1024, 1024);
  lnb_kernel<<<NTOK, 256, 0, stream>>>(res2b, g2, b2, h2);
  gemm8ph<2><<<dim3(16, 16), 512, 0, stream>>>(h2, w1_b, (void*)ffm, (void*)ffm,
                                               (void*)ffm, (void*)ffm, 4096, 1024, 1024);
  gemm8ph<0><<<dim3(16, 4, 4), 512, 0, stream>>>(ffm, w2_b, (void*)p0, (void*)p1,
                                                 (void*)p2, (void*)p3, 1024, 1024, 4096);
  red4_kernel<<<2048, 256, 0, stream>>>(p0, p1, p2, p3, x, out);
}